// Round 5
// baseline (511.906 us; speedup 1.0000x reference)
//
#include <hip/hip_runtime.h>
#include <hip/hip_fp16.h>

#define NN 100000
#define NE 3200000
#define FIN 300
#define HID 16
#define NC 10

#define NPB 64                  // nodes per bucket
#define NB 1563                 // ceil(NN / NPB)
#define NSEG 512                // edge segments
#define EPS (NE / NSEG)         // 6250 edges per segment
#define NCH 8                   // chunks for the seg-scan
#define SEGPC (NSEG / NCH)      // 64 segs per chunk
#define CAP 4096                // max bucket size (mean 2048, sd ~45)

#define NTILE 6250              // NN / 16 node-tiles for MFMA k_xw

typedef __fp16 h2 __attribute__((ext_vector_type(2)));
typedef __fp16 h8 __attribute__((ext_vector_type(8)));
typedef float f32x4 __attribute__((ext_vector_type(4)));

__device__ __forceinline__ float h2f_lo(int y) {
    __half_raw hr; hr.x = (unsigned short)(y & 0xFFFF);
    __half h; *(__half_raw*)&h = hr;
    return __half2float(h);
}
__device__ __forceinline__ int f2h_us(float f) {
    __half h = __float2half(f);
    return (int)(*(__half_raw*)&h).x;
}

// ---- wdeg init: self-loop weight 1.0 ---------------------------------------

__global__ void k_winit(float* __restrict__ wdeg) {
    int i = blockIdx.x * 256 + threadIdx.x;
    if (i < NN) wdeg[i] = 1.0f;
}

// ---- phase 1: per-segment histogram over buckets ---------------------------

__global__ void k_hist(const int* __restrict__ col, int* __restrict__ hist) {
    __shared__ int bins[NB];
    int seg = blockIdx.x, tid = threadIdx.x;
    for (int i = tid; i < NB; i += 256) bins[i] = 0;
    __syncthreads();
    int base = seg * EPS;
    for (int k = tid; k < EPS; k += 256) atomicAdd(&bins[col[base + k] >> 6], 1);
    __syncthreads();
    for (int i = tid; i < NB; i += 256) hist[seg * NB + i] = bins[i];
}

// ---- phase 2: parallel scan of hist over segs ------------------------------

__global__ void k_psumA(const int* __restrict__ hist, int* __restrict__ psum) {
    int bin = blockIdx.x * 256 + threadIdx.x;
    int ch = blockIdx.y;
    if (bin >= NB) return;
    int s = 0;
    for (int seg = ch * SEGPC; seg < (ch + 1) * SEGPC; ++seg) s += hist[seg * NB + bin];
    psum[ch * NB + bin] = s;
}

__global__ void k_psumB(int* __restrict__ psum, int* __restrict__ bstart) {
    int bin = blockIdx.x * 256 + threadIdx.x;
    if (bin >= NB) return;
    int run = 0;
    #pragma unroll
    for (int ch = 0; ch < NCH; ++ch) {
        int v = psum[ch * NB + bin];
        psum[ch * NB + bin] = run;
        run += v;
    }
    bstart[bin] = run;
}

__global__ void k_scanBkt(int* __restrict__ bstart) {
    __shared__ int lsum[256];
    int t = threadIdx.x;
    const int M = (NB + 255) / 256;   // 7
    int base = t * M;
    int s = 0;
    for (int q = 0; q < M; ++q) { int i = base + q; if (i < NB) s += bstart[i]; }
    lsum[t] = s; __syncthreads();
    for (int off = 1; off < 256; off <<= 1) {
        int add = (t >= off) ? lsum[t - off] : 0;
        __syncthreads(); lsum[t] += add; __syncthreads();
    }
    int run = (t > 0) ? lsum[t - 1] : 0;
    for (int q = 0; q < M; ++q) {
        int i = base + q;
        if (i < NB) { int v = bstart[i]; bstart[i] = run; run += v; }
    }
    if (t == 255) bstart[NB] = run;   // = NE
}

__global__ void k_applyC(int* __restrict__ hist, const int* __restrict__ psum,
                         const int* __restrict__ bstart) {
    int bin = blockIdx.x * 256 + threadIdx.x;
    int ch = blockIdx.y;
    if (bin >= NB) return;
    int run = bstart[bin] + psum[ch * NB + bin];
    for (int seg = ch * SEGPC; seg < (ch + 1) * SEGPC; ++seg) {
        int idx = seg * NB + bin;
        int v = hist[idx];
        hist[idx] = run;
        run += v;
    }
}

// ---- phase 3: LDS-sorted scatter + wdeg atomics, coalesced int2 writes -----
// record: .x = row | (col&63)<<17 ; .y = w_half | bin<<16 (bin bits scrubbed later)

__launch_bounds__(256)
__global__ void k_scatter(const int* __restrict__ row, const int* __restrict__ col,
                          const float* __restrict__ w, const int* __restrict__ hist,
                          int2* __restrict__ bkt, float* __restrict__ wdeg) {
    __shared__ int bins[NB];
    __shared__ int cur[NB];
    __shared__ int lsum[256];
    __shared__ int2 sdata[EPS];
    int seg = blockIdx.x, tid = threadIdx.x;
    for (int i = tid; i < NB; i += 256) bins[i] = 0;
    __syncthreads();
    int base = seg * EPS;
    for (int k = tid; k < EPS; k += 256) atomicAdd(&bins[col[base + k] >> 6], 1);
    __syncthreads();
    // block exclusive scan of bins
    const int M = (NB + 255) / 256;
    int lbase = tid * M;
    int s = 0;
    for (int q = 0; q < M; ++q) { int i = lbase + q; if (i < NB) s += bins[i]; }
    lsum[tid] = s; __syncthreads();
    for (int off = 1; off < 256; off <<= 1) {
        int add = (tid >= off) ? lsum[tid - off] : 0;
        __syncthreads(); lsum[tid] += add; __syncthreads();
    }
    int run = (tid > 0) ? lsum[tid - 1] : 0;
    for (int q = 0; q < M; ++q) {
        int i = lbase + q;
        if (i < NB) { int v = bins[i]; bins[i] = run; cur[i] = run; run += v; }
    }
    __syncthreads();
    // place into LDS sorted by bin; accumulate weighted degree globally
    for (int k = tid; k < EPS; k += 256) {
        int e = base + k;
        int r = row[e], c = col[e];
        float wv = w[e];
        atomicAdd(&wdeg[c], wv);
        int bin = c >> 6;
        int pos = atomicAdd(&cur[bin], 1);
        sdata[pos] = make_int2(r | ((c & 63) << 17), f2h_us(wv) | (bin << 16));
    }
    __syncthreads();
    // bins[bin] := global_start(seg,bin) - lds_start(bin)
    for (int i = tid; i < NB; i += 256) bins[i] = hist[seg * NB + i] - bins[i];
    __syncthreads();
    for (int j = tid; j < EPS; j += 256) {
        int2 d = sdata[j];
        int bin = ((unsigned)d.y) >> 16;
        bkt[bins[bin] + j] = d;
    }
}

// ---- x @ W1 via MFMA (f16 inputs, fp32 acc), pre-scaled by dinv, fp16 out --
// Wave tile = 16 nodes x 16 cols over K=320 (zero-padded from 300): 10x
// v_mfma_f32_16x16x32_f16. W1 frag-ordered in 10 KB LDS; A streamed straight
// from global (32 B contiguous per lane per k-step).

__launch_bounds__(256)
__global__ void k_xw(const float* __restrict__ x, const float* __restrict__ W1,
                     const float* __restrict__ wdeg, int2* __restrict__ xws) {
    __shared__ h8 bfrag[10][64];        // 10 KB, frag-ordered W1 in f16
    int tid = threadIdx.x;
    // stage + convert W1: entry (s,l): col=l&15, k = 32s + 8*(l>>4) + j
    for (int e2 = tid; e2 < 640; e2 += 256) {
        int s = e2 >> 6, l = e2 & 63;
        int g = l >> 4, c = l & 15;
        int kb = 32 * s + 8 * g;
        float f[8];
        #pragma unroll
        for (int j = 0; j < 8; ++j) {
            int k = kb + j;
            f[j] = (k < FIN) ? W1[k * HID + c] : 0.f;
        }
        h2 q0 = __builtin_amdgcn_cvt_pkrtz(f[0], f[1]);
        h2 q1 = __builtin_amdgcn_cvt_pkrtz(f[2], f[3]);
        h2 q2 = __builtin_amdgcn_cvt_pkrtz(f[4], f[5]);
        h2 q3 = __builtin_amdgcn_cvt_pkrtz(f[6], f[7]);
        h8 v;
        v[0] = q0[0]; v[1] = q0[1]; v[2] = q1[0]; v[3] = q1[1];
        v[4] = q2[0]; v[5] = q2[1]; v[6] = q3[0]; v[7] = q3[1];
        bfrag[s][l] = v;
    }
    __syncthreads();
    int widx = tid >> 6, lane = tid & 63;
    int g = lane >> 4, rr = lane & 15;
    int gw = blockIdx.x * 4 + widx;
    unsigned short* op = (unsigned short*)xws;
    #pragma unroll 1
    for (int t = 0; t < 2; ++t) {
        int tile = gw * 2 + t;
        if (tile >= NTILE) break;
        int n0 = tile * 16;
        const float* xrow = x + (long)(n0 + rr) * FIN;
        f32x4 acc = {0.f, 0.f, 0.f, 0.f};
        #pragma unroll
        for (int s = 0; s < 9; ++s) {
            int k0 = 32 * s + 8 * g;
            f32x4 u0 = *(const f32x4*)(xrow + k0);
            f32x4 u1 = *(const f32x4*)(xrow + k0 + 4);
            h2 p0 = __builtin_amdgcn_cvt_pkrtz(u0[0], u0[1]);
            h2 p1 = __builtin_amdgcn_cvt_pkrtz(u0[2], u0[3]);
            h2 p2 = __builtin_amdgcn_cvt_pkrtz(u1[0], u1[1]);
            h2 p3 = __builtin_amdgcn_cvt_pkrtz(u1[2], u1[3]);
            h8 a;
            a[0] = p0[0]; a[1] = p0[1]; a[2] = p1[0]; a[3] = p1[1];
            a[4] = p2[0]; a[5] = p2[1]; a[6] = p3[0]; a[7] = p3[1];
            acc = __builtin_amdgcn_mfma_f32_16x16x32_f16(a, bfrag[s][lane], acc, 0, 0, 0);
        }
        {   // K tail: k 288..299 valid, 300..319 zero
            int k0 = 288 + 8 * g;
            f32x4 z = {0.f, 0.f, 0.f, 0.f};
            f32x4 u0 = (g < 2) ? *(const f32x4*)(xrow + k0) : z;
            f32x4 u1 = (g == 0) ? *(const f32x4*)(xrow + k0 + 4) : z;
            h2 p0 = __builtin_amdgcn_cvt_pkrtz(u0[0], u0[1]);
            h2 p1 = __builtin_amdgcn_cvt_pkrtz(u0[2], u0[3]);
            h2 p2 = __builtin_amdgcn_cvt_pkrtz(u1[0], u1[1]);
            h2 p3 = __builtin_amdgcn_cvt_pkrtz(u1[2], u1[3]);
            h8 a;
            a[0] = p0[0]; a[1] = p0[1]; a[2] = p1[0]; a[3] = p1[1];
            a[4] = p2[0]; a[5] = p2[1]; a[6] = p3[0]; a[7] = p3[1];
            acc = __builtin_amdgcn_mfma_f32_16x16x32_f16(a, bfrag[9][lane], acc, 0, 0, 0);
        }
        // C/D: col = lane&15 (=rr), row-in-tile = g*4 + r2
        #pragma unroll
        for (int r2 = 0; r2 < 4; ++r2) {
            int node = n0 + g * 4 + r2;
            float di = rsqrtf(wdeg[node]);
            op[(long)node * HID + rr] = (unsigned short)f2h_us(di * acc[r2]);
        }
    }
}

// ---- fused refine + layer-1 gather -----------------------------------------
// Per bucket: count/scan/sort edges into LDS (node order), write sorted back
// for k_gather2, then gather layer 1 straight from LDS (broadcast reads),
// fused b1/relu/@W2, fp16 store. dinv = rsqrt(wdeg) inline.

__launch_bounds__(256)
__global__ void k_rg1(const int* __restrict__ bstart, int2* __restrict__ bkt,
                      const float* __restrict__ wdeg, int* __restrict__ ns,
                      const unsigned short* __restrict__ xwsh,
                      const float* __restrict__ b1, const float* __restrict__ W2,
                      unsigned short* __restrict__ hw2s) {
    __shared__ int cnt[NPB];
    __shared__ int cur[NPB];
    __shared__ int off[NPB + 1];
    __shared__ int2 sorted[CAP];
    __shared__ float w2s[HID * NC];
    __shared__ float b1s[HID];
    int b = blockIdx.x, tid = threadIdx.x;
    if (tid < HID * NC) w2s[tid] = W2[tid];
    if (tid < HID) b1s[tid] = b1[tid];
    int s = bstart[b], e = bstart[b + 1];
    int size = e - s; if (size > CAP) size = CAP;   // 45-sigma guard, never hit
    if (tid < NPB) cnt[tid] = 0;
    __syncthreads();
    for (int k = tid; k < size; k += 256) {
        int2 d = bkt[s + k];
        atomicAdd(&cnt[(d.x >> 17) & 63], 1);
    }
    __syncthreads();
    int v = (tid < NPB) ? cnt[tid] : 0;
    for (int o = 1; o < NPB; o <<= 1) {
        int add = (tid >= o && tid < NPB) ? cnt[tid - o] : 0;
        __syncthreads();
        if (tid < NPB) cnt[tid] += add;
        __syncthreads();
    }
    if (tid < NPB) {
        int excl = cnt[tid] - v;
        cur[tid] = excl;
        off[tid] = excl;
        int node = b * NPB + tid;
        if (node < NN) ns[node] = s + excl;
    }
    if (tid == 0) off[NPB] = size;
    if (b == NB - 1 && tid == 0) ns[NN] = e;
    __syncthreads();
    for (int k = tid; k < size; k += 256) {
        int2 d = bkt[s + k];
        int cl = (d.x >> 17) & 63;
        int pos = atomicAdd(&cur[cl], 1);
        sorted[pos] = make_int2(d.x & 0x1FFFF, d.y & 0xFFFF);
    }
    __syncthreads();
    // write back node-sorted edges for k_gather2 (fire-and-forget stores)
    for (int k = tid; k < size; k += 256) bkt[s + k] = sorted[k];
    // layer-1 gather from LDS
    int c = tid & 15, g = tid >> 4;   // g in 0..15
    #pragma unroll 1
    for (int q = 0; q < 4; ++q) {
        int nl = g + 16 * q;
        int node = b * NPB + nl;
        int o0 = off[nl], o1 = off[nl + 1];
        float acc = 0.f;
        int k = o0;
        for (; k + 4 <= o1; k += 4) {
            int2 e0 = sorted[k], e1 = sorted[k + 1], e2 = sorted[k + 2], e3 = sorted[k + 3];
            __half_raw h0; h0.x = xwsh[e0.x * HID + c];
            __half_raw h1; h1.x = xwsh[e1.x * HID + c];
            __half_raw h2; h2.x = xwsh[e2.x * HID + c];
            __half_raw h3; h3.x = xwsh[e3.x * HID + c];
            acc = fmaf(h2f_lo(e0.y), __half2float(*(__half*)&h0), acc);
            acc = fmaf(h2f_lo(e1.y), __half2float(*(__half*)&h1), acc);
            acc = fmaf(h2f_lo(e2.y), __half2float(*(__half*)&h2), acc);
            acc = fmaf(h2f_lo(e3.y), __half2float(*(__half*)&h3), acc);
        }
        for (; k < o1; ++k) {
            int2 e0 = sorted[k];
            __half_raw h0; h0.x = xwsh[e0.x * HID + c];
            acc = fmaf(h2f_lo(e0.y), __half2float(*(__half*)&h0), acc);
        }
        if (node < NN) {
            { __half_raw hs; hs.x = xwsh[node * HID + c]; acc += __half2float(*(__half*)&hs); }
            float dc = rsqrtf(wdeg[node]);
            float h = fmaxf(fmaf(dc, acc, b1s[c]), 0.f);
            float acc2 = 0.f;
            int jj = (c < NC) ? c : 0;
            #pragma unroll
            for (int k2 = 0; k2 < HID; ++k2) {
                float hk = __shfl(h, k2, HID);
                acc2 = fmaf(hk, w2s[k2 * NC + jj], acc2);
            }
            if (c < NC) hw2s[node * NC + c] = (unsigned short)f2h_us(dc * acc2);
        }
    }
}

// ---- layer 2 pull-gather, fused b2/log_softmax -----------------------------

__global__ void k_gather2(const int* __restrict__ ns, const int2* __restrict__ bkt,
                          const unsigned short* __restrict__ hw2s,
                          const float* __restrict__ wdeg, const float* __restrict__ b2,
                          float* __restrict__ out) {
    int t = blockIdx.x * 256 + threadIdx.x;
    int i = t >> 4, j = t & 15;
    int s = ns[i], e = ns[i + 1];
    float v;
    if (j < NC) {
        float acc = 0.f;
        int k = s;
        for (; k + 4 <= e; k += 4) {
            int2 e0 = bkt[k], e1 = bkt[k + 1], e2 = bkt[k + 2], e3 = bkt[k + 3];
            __half_raw h0; h0.x = hw2s[e0.x * NC + j];
            __half_raw h1; h1.x = hw2s[e1.x * NC + j];
            __half_raw h2; h2.x = hw2s[e2.x * NC + j];
            __half_raw h3; h3.x = hw2s[e3.x * NC + j];
            acc = fmaf(h2f_lo(e0.y), __half2float(*(__half*)&h0), acc);
            acc = fmaf(h2f_lo(e1.y), __half2float(*(__half*)&h1), acc);
            acc = fmaf(h2f_lo(e2.y), __half2float(*(__half*)&h2), acc);
            acc = fmaf(h2f_lo(e3.y), __half2float(*(__half*)&h3), acc);
        }
        for (; k < e; ++k) {
            int2 e0 = bkt[k];
            __half_raw h0; h0.x = hw2s[e0.x * NC + j];
            acc = fmaf(h2f_lo(e0.y), __half2float(*(__half*)&h0), acc);
        }
        { __half_raw hs; hs.x = hw2s[i * NC + j]; acc += __half2float(*(__half*)&hs); }
        v = fmaf(rsqrtf(wdeg[i]), acc, b2[j]);
    } else {
        v = -1e30f;
    }
    float m = v;
    #pragma unroll
    for (int mask = 8; mask > 0; mask >>= 1) m = fmaxf(m, __shfl_xor(m, mask, HID));
    float ev = (j < NC) ? __expf(v - m) : 0.f;
    float ssum = ev;
    #pragma unroll
    for (int mask = 8; mask > 0; mask >>= 1) ssum += __shfl_xor(ssum, mask, HID);
    if (j < NC) out[(long)i * NC + j] = v - m - __logf(ssum);
}

// ---- launch -----------------------------------------------------------------

extern "C" void kernel_launch(void* const* d_in, const int* in_sizes, int n_in,
                              void* d_out, int out_size, void* d_ws, size_t ws_size,
                              hipStream_t stream) {
    const float* x  = (const float*)d_in[0];
    const int*   ei = (const int*)d_in[1];
    const float* ew = (const float*)d_in[2];
    const float* W1 = (const float*)d_in[3];
    const float* b1 = (const float*)d_in[4];
    const float* W2 = (const float*)d_in[5];
    const float* b2 = (const float*)d_in[6];
    float* out = (float*)d_out;

    const int* row = ei;
    const int* col = ei + NE;

    // workspace (words); xws overlays hist (dead after k_scatter)
    int*   hist   = (int*)d_ws;                    // NSEG*NB = 800,256
    int*   psum   = hist + NSEG * NB;              // NCH*NB  = 12,504
    int*   bstart = psum + NCH * NB;               // NB+1    = 1,564
    float* wdeg   = (float*)(bstart + NB + 1);     // 100,000
    int*   ns     = (int*)(wdeg + NN);             // 100,001
    size_t o = (size_t)(NSEG * NB) + NCH * NB + (NB + 1) + NN + (NN + 1);
    o = (o + 1) & ~(size_t)1;                      // 8B align for int2
    int2*  bkt    = (int2*)((int*)d_ws + o);       // NE int2 = 6,400,000 w
    unsigned short* hw2s = (unsigned short*)(bkt + NE);   // NN*NC halves = 500,000 w
    int2*  xws    = (int2*)hist;                   // NN*4 int2 = 800,000 w overlay
    // total ~= 7,914,326 words = 31.7 MB

    k_winit<<<(NN + 255) / 256, 256, 0, stream>>>(wdeg);
    k_hist<<<NSEG, 256, 0, stream>>>(col, hist);
    k_psumA<<<dim3((NB + 255) / 256, NCH), 256, 0, stream>>>(hist, psum);
    k_psumB<<<(NB + 255) / 256, 256, 0, stream>>>(psum, bstart);
    k_scanBkt<<<1, 256, 0, stream>>>(bstart);
    k_applyC<<<dim3((NB + 255) / 256, NCH), 256, 0, stream>>>(hist, psum, bstart);
    k_scatter<<<NSEG, 256, 0, stream>>>(row, col, ew, hist, bkt, wdeg);

    // 782 blocks x 4 waves x 2 tiles = 6256 >= 6250 tiles
    k_xw<<<782, 256, 0, stream>>>(x, W1, wdeg, xws);
    k_rg1<<<NB, 256, 0, stream>>>(bstart, bkt, wdeg, ns, (const unsigned short*)xws,
                                  b1, W2, hw2s);
    k_gather2<<<(NN * 16) / 256, 256, 0, stream>>>(ns, bkt, hw2s, wdeg, b2, out);
}

// Round 6
// 385.955 us; speedup vs baseline: 1.3263x; 1.3263x over previous
//
#include <hip/hip_runtime.h>
#include <hip/hip_fp16.h>

#define NN 100000
#define NE 3200000
#define FIN 300
#define HID 16
#define NC 10

#define NPB 64                  // nodes per bucket
#define NB 1563                 // ceil(NN / NPB)
#define NSEG 512                // edge segments
#define EPS (NE / NSEG)         // 6250 edges per segment
#define NCH 8                   // chunks for the seg-scan
#define SEGPC (NSEG / NCH)      // 64 segs per chunk
#define CAP 4096                // max bucket size (mean 2048, sd ~45)

#define NTILE 6250              // NN / 16 node-tiles for MFMA k_xw

typedef __fp16 h2 __attribute__((ext_vector_type(2)));
typedef __fp16 h8 __attribute__((ext_vector_type(8)));
typedef float f32x4 __attribute__((ext_vector_type(4)));

__device__ __forceinline__ float h2f_lo(int y) {
    __half_raw hr; hr.x = (unsigned short)(y & 0xFFFF);
    __half h; *(__half_raw*)&h = hr;
    return __half2float(h);
}
__device__ __forceinline__ int f2h_us(float f) {
    __half h = __float2half(f);
    return (int)(*(__half_raw*)&h).x;
}

// ---- phase 1: per-segment histogram over buckets ---------------------------

__global__ void k_hist(const int* __restrict__ col, int* __restrict__ hist) {
    __shared__ int bins[NB];
    int seg = blockIdx.x, tid = threadIdx.x;
    for (int i = tid; i < NB; i += 256) bins[i] = 0;
    __syncthreads();
    int base = seg * EPS;
    for (int k = tid; k < EPS; k += 256) atomicAdd(&bins[col[base + k] >> 6], 1);
    __syncthreads();
    for (int i = tid; i < NB; i += 256) hist[seg * NB + i] = bins[i];
}

// ---- phase 2: parallel scan of hist over segs ------------------------------

__global__ void k_psumA(const int* __restrict__ hist, int* __restrict__ psum) {
    int bin = blockIdx.x * 256 + threadIdx.x;
    int ch = blockIdx.y;
    if (bin >= NB) return;
    int s = 0;
    for (int seg = ch * SEGPC; seg < (ch + 1) * SEGPC; ++seg) s += hist[seg * NB + bin];
    psum[ch * NB + bin] = s;
}

__global__ void k_psumB(int* __restrict__ psum, int* __restrict__ bstart) {
    int bin = blockIdx.x * 256 + threadIdx.x;
    if (bin >= NB) return;
    int run = 0;
    #pragma unroll
    for (int ch = 0; ch < NCH; ++ch) {
        int v = psum[ch * NB + bin];
        psum[ch * NB + bin] = run;
        run += v;
    }
    bstart[bin] = run;
}

__global__ void k_scanBkt(int* __restrict__ bstart) {
    __shared__ int lsum[256];
    int t = threadIdx.x;
    const int M = (NB + 255) / 256;   // 7
    int base = t * M;
    int s = 0;
    for (int q = 0; q < M; ++q) { int i = base + q; if (i < NB) s += bstart[i]; }
    lsum[t] = s; __syncthreads();
    for (int off = 1; off < 256; off <<= 1) {
        int add = (t >= off) ? lsum[t - off] : 0;
        __syncthreads(); lsum[t] += add; __syncthreads();
    }
    int run = (t > 0) ? lsum[t - 1] : 0;
    for (int q = 0; q < M; ++q) {
        int i = base + q;
        if (i < NB) { int v = bstart[i]; bstart[i] = run; run += v; }
    }
    if (t == 255) bstart[NB] = run;   // = NE
}

__global__ void k_applyC(int* __restrict__ hist, const int* __restrict__ psum,
                         const int* __restrict__ bstart) {
    int bin = blockIdx.x * 256 + threadIdx.x;
    int ch = blockIdx.y;
    if (bin >= NB) return;
    int run = bstart[bin] + psum[ch * NB + bin];
    for (int seg = ch * SEGPC; seg < (ch + 1) * SEGPC; ++seg) {
        int idx = seg * NB + bin;
        int v = hist[idx];
        hist[idx] = run;
        run += v;
    }
}

// ---- phase 3: LDS-sorted scatter, coalesced int2 writes --------------------
// record: .x = row | (col&63)<<17 ; .y = w_half | bin<<16 (bin bits scrubbed later)
// NO global atomics here: device-scope atomics are memory-side on MI355X
// (per-XCD L2 non-coherent) -- round-5 regression, +120us.

__launch_bounds__(256)
__global__ void k_scatter(const int* __restrict__ row, const int* __restrict__ col,
                          const float* __restrict__ w, const int* __restrict__ hist,
                          int2* __restrict__ bkt) {
    __shared__ int bins[NB];
    __shared__ int cur[NB];
    __shared__ int lsum[256];
    __shared__ int2 sdata[EPS];
    int seg = blockIdx.x, tid = threadIdx.x;
    for (int i = tid; i < NB; i += 256) bins[i] = 0;
    __syncthreads();
    int base = seg * EPS;
    for (int k = tid; k < EPS; k += 256) atomicAdd(&bins[col[base + k] >> 6], 1);
    __syncthreads();
    // block exclusive scan of bins
    const int M = (NB + 255) / 256;
    int lbase = tid * M;
    int s = 0;
    for (int q = 0; q < M; ++q) { int i = lbase + q; if (i < NB) s += bins[i]; }
    lsum[tid] = s; __syncthreads();
    for (int off = 1; off < 256; off <<= 1) {
        int add = (tid >= off) ? lsum[tid - off] : 0;
        __syncthreads(); lsum[tid] += add; __syncthreads();
    }
    int run = (tid > 0) ? lsum[tid - 1] : 0;
    for (int q = 0; q < M; ++q) {
        int i = lbase + q;
        if (i < NB) { int v = bins[i]; bins[i] = run; cur[i] = run; run += v; }
    }
    __syncthreads();
    // place into LDS sorted by bin
    for (int k = tid; k < EPS; k += 256) {
        int e = base + k;
        int r = row[e], c = col[e];
        int bin = c >> 6;
        int pos = atomicAdd(&cur[bin], 1);
        sdata[pos] = make_int2(r | ((c & 63) << 17), f2h_us(w[e]) | (bin << 16));
    }
    __syncthreads();
    // bins[bin] := global_start(seg,bin) - lds_start(bin)
    for (int i = tid; i < NB; i += 256) bins[i] = hist[seg * NB + i] - bins[i];
    __syncthreads();
    for (int j = tid; j < EPS; j += 256) {
        int2 d = sdata[j];
        int bin = ((unsigned)d.y) >> 16;
        bkt[bins[bin] + j] = d;
    }
}

// ---- x @ W1 via MFMA + fused per-bucket wdeg/dinv --------------------------
// Block = 128 nodes = buckets 2b, 2b+1 (bkt is bucket-contiguous after
// scatter; record carries bin in .y>>16). Phase A: stream the 2 buckets'
// edges, LDS-atomicAdd wdeg[128] (legal LDS atomics, not global), write
// dinv[] for rg1/gather2. Phase B: 16x16 MFMA tiles over K=320 as before,
// scaling the C-write by LDS dinv.

__launch_bounds__(256)
__global__ void k_xw(const float* __restrict__ x, const float* __restrict__ W1,
                     const int* __restrict__ bstart, const int2* __restrict__ bkt,
                     float* __restrict__ dinv, int2* __restrict__ xws) {
    __shared__ h8 bfrag[10][64];        // 10 KB, frag-ordered W1 in f16
    __shared__ float wd[128];
    int tid = threadIdx.x;
    if (tid < 128) wd[tid] = 1.0f;      // self-loop weight
    // stage + convert W1: entry (s,l): col=l&15, k = 32s + 8*(l>>4) + j
    for (int e2 = tid; e2 < 640; e2 += 256) {
        int s = e2 >> 6, l = e2 & 63;
        int g = l >> 4, c = l & 15;
        int kb = 32 * s + 8 * g;
        float f[8];
        #pragma unroll
        for (int j = 0; j < 8; ++j) {
            int k = kb + j;
            f[j] = (k < FIN) ? W1[k * HID + c] : 0.f;
        }
        h2 q0 = __builtin_amdgcn_cvt_pkrtz(f[0], f[1]);
        h2 q1 = __builtin_amdgcn_cvt_pkrtz(f[2], f[3]);
        h2 q2 = __builtin_amdgcn_cvt_pkrtz(f[4], f[5]);
        h2 q3 = __builtin_amdgcn_cvt_pkrtz(f[6], f[7]);
        h8 v;
        v[0] = q0[0]; v[1] = q0[1]; v[2] = q1[0]; v[3] = q1[1];
        v[4] = q2[0]; v[5] = q2[1]; v[6] = q3[0]; v[7] = q3[1];
        bfrag[s][l] = v;
    }
    __syncthreads();
    // phase A: wdeg for buckets 2b, 2b+1
    int b0 = blockIdx.x * 2;
    int es = bstart[b0];
    int ee = bstart[(b0 + 2 <= NB) ? b0 + 2 : NB];
    for (int k = es + tid; k < ee; k += 256) {
        int2 d = bkt[k];
        int bin = ((unsigned)d.y) >> 16;
        int nl = ((bin - b0) << 6) | ((d.x >> 17) & 63);
        atomicAdd(&wd[nl], h2f_lo(d.y));
    }
    __syncthreads();
    if (tid < 128) {
        int node = blockIdx.x * 128 + tid;
        float di = rsqrtf(wd[tid]);
        wd[tid] = di;
        if (node < NN) dinv[node] = di;
    }
    __syncthreads();
    // phase B: MFMA
    int widx = tid >> 6, lane = tid & 63;
    int g = lane >> 4, rr = lane & 15;
    int gw = blockIdx.x * 4 + widx;
    unsigned short* op = (unsigned short*)xws;
    #pragma unroll 1
    for (int t = 0; t < 2; ++t) {
        int tile = gw * 2 + t;
        if (tile >= NTILE) break;
        int n0 = tile * 16;
        const float* xrow = x + (long)(n0 + rr) * FIN;
        f32x4 acc = {0.f, 0.f, 0.f, 0.f};
        #pragma unroll
        for (int s = 0; s < 9; ++s) {
            int k0 = 32 * s + 8 * g;
            f32x4 u0 = *(const f32x4*)(xrow + k0);
            f32x4 u1 = *(const f32x4*)(xrow + k0 + 4);
            h2 p0 = __builtin_amdgcn_cvt_pkrtz(u0[0], u0[1]);
            h2 p1 = __builtin_amdgcn_cvt_pkrtz(u0[2], u0[3]);
            h2 p2 = __builtin_amdgcn_cvt_pkrtz(u1[0], u1[1]);
            h2 p3 = __builtin_amdgcn_cvt_pkrtz(u1[2], u1[3]);
            h8 a;
            a[0] = p0[0]; a[1] = p0[1]; a[2] = p1[0]; a[3] = p1[1];
            a[4] = p2[0]; a[5] = p2[1]; a[6] = p3[0]; a[7] = p3[1];
            acc = __builtin_amdgcn_mfma_f32_16x16x32_f16(a, bfrag[s][lane], acc, 0, 0, 0);
        }
        {   // K tail: k 288..299 valid, 300..319 zero
            int k0 = 288 + 8 * g;
            f32x4 z = {0.f, 0.f, 0.f, 0.f};
            f32x4 u0 = (g < 2) ? *(const f32x4*)(xrow + k0) : z;
            f32x4 u1 = (g == 0) ? *(const f32x4*)(xrow + k0 + 4) : z;
            h2 p0 = __builtin_amdgcn_cvt_pkrtz(u0[0], u0[1]);
            h2 p1 = __builtin_amdgcn_cvt_pkrtz(u0[2], u0[3]);
            h2 p2 = __builtin_amdgcn_cvt_pkrtz(u1[0], u1[1]);
            h2 p3 = __builtin_amdgcn_cvt_pkrtz(u1[2], u1[3]);
            h8 a;
            a[0] = p0[0]; a[1] = p0[1]; a[2] = p1[0]; a[3] = p1[1];
            a[4] = p2[0]; a[5] = p2[1]; a[6] = p3[0]; a[7] = p3[1];
            acc = __builtin_amdgcn_mfma_f32_16x16x32_f16(a, bfrag[9][lane], acc, 0, 0, 0);
        }
        // C/D: col = lane&15 (=rr), row-in-tile = g*4 + r2
        #pragma unroll
        for (int r2 = 0; r2 < 4; ++r2) {
            int node = n0 + g * 4 + r2;
            float di = wd[node - blockIdx.x * 128];
            op[(long)node * HID + rr] = (unsigned short)f2h_us(di * acc[r2]);
        }
    }
}

// ---- fused refine + layer-1 gather -----------------------------------------
// Per bucket: count/scan/sort edges into LDS (node order), write sorted back
// for k_gather2, then gather layer 1 straight from LDS (broadcast reads),
// fused b1/relu/@W2, fp16 store. dinv read from k_xw's output.

__launch_bounds__(256)
__global__ void k_rg1(const int* __restrict__ bstart, int2* __restrict__ bkt,
                      const float* __restrict__ dinv, int* __restrict__ ns,
                      const unsigned short* __restrict__ xwsh,
                      const float* __restrict__ b1, const float* __restrict__ W2,
                      unsigned short* __restrict__ hw2s) {
    __shared__ int cnt[NPB];
    __shared__ int cur[NPB];
    __shared__ int off[NPB + 1];
    __shared__ int2 sorted[CAP];
    __shared__ float w2s[HID * NC];
    __shared__ float b1s[HID];
    int b = blockIdx.x, tid = threadIdx.x;
    if (tid < HID * NC) w2s[tid] = W2[tid];
    if (tid < HID) b1s[tid] = b1[tid];
    int s = bstart[b], e = bstart[b + 1];
    int size = e - s; if (size > CAP) size = CAP;   // 45-sigma guard, never hit
    if (tid < NPB) cnt[tid] = 0;
    __syncthreads();
    for (int k = tid; k < size; k += 256) {
        int2 d = bkt[s + k];
        atomicAdd(&cnt[(d.x >> 17) & 63], 1);
    }
    __syncthreads();
    int v = (tid < NPB) ? cnt[tid] : 0;
    for (int o = 1; o < NPB; o <<= 1) {
        int add = (tid >= o && tid < NPB) ? cnt[tid - o] : 0;
        __syncthreads();
        if (tid < NPB) cnt[tid] += add;
        __syncthreads();
    }
    if (tid < NPB) {
        int excl = cnt[tid] - v;
        cur[tid] = excl;
        off[tid] = excl;
        int node = b * NPB + tid;
        if (node < NN) ns[node] = s + excl;
    }
    if (tid == 0) off[NPB] = size;
    if (b == NB - 1 && tid == 0) ns[NN] = e;
    __syncthreads();
    for (int k = tid; k < size; k += 256) {
        int2 d = bkt[s + k];
        int cl = (d.x >> 17) & 63;
        int pos = atomicAdd(&cur[cl], 1);
        sorted[pos] = make_int2(d.x & 0x1FFFF, d.y & 0xFFFF);
    }
    __syncthreads();
    // write back node-sorted edges for k_gather2 (fire-and-forget stores)
    for (int k = tid; k < size; k += 256) bkt[s + k] = sorted[k];
    // layer-1 gather from LDS
    int c = tid & 15, g = tid >> 4;   // g in 0..15
    #pragma unroll 1
    for (int q = 0; q < 4; ++q) {
        int nl = g + 16 * q;
        int node = b * NPB + nl;
        int o0 = off[nl], o1 = off[nl + 1];
        float acc = 0.f;
        int k = o0;
        for (; k + 4 <= o1; k += 4) {
            int2 e0 = sorted[k], e1 = sorted[k + 1], e2 = sorted[k + 2], e3 = sorted[k + 3];
            __half_raw h0; h0.x = xwsh[e0.x * HID + c];
            __half_raw h1; h1.x = xwsh[e1.x * HID + c];
            __half_raw h2; h2.x = xwsh[e2.x * HID + c];
            __half_raw h3; h3.x = xwsh[e3.x * HID + c];
            acc = fmaf(h2f_lo(e0.y), __half2float(*(__half*)&h0), acc);
            acc = fmaf(h2f_lo(e1.y), __half2float(*(__half*)&h1), acc);
            acc = fmaf(h2f_lo(e2.y), __half2float(*(__half*)&h2), acc);
            acc = fmaf(h2f_lo(e3.y), __half2float(*(__half*)&h3), acc);
        }
        for (; k < o1; ++k) {
            int2 e0 = sorted[k];
            __half_raw h0; h0.x = xwsh[e0.x * HID + c];
            acc = fmaf(h2f_lo(e0.y), __half2float(*(__half*)&h0), acc);
        }
        if (node < NN) {
            { __half_raw hs; hs.x = xwsh[node * HID + c]; acc += __half2float(*(__half*)&hs); }
            float dc = dinv[node];
            float h = fmaxf(fmaf(dc, acc, b1s[c]), 0.f);
            float acc2 = 0.f;
            int jj = (c < NC) ? c : 0;
            #pragma unroll
            for (int k2 = 0; k2 < HID; ++k2) {
                float hk = __shfl(h, k2, HID);
                acc2 = fmaf(hk, w2s[k2 * NC + jj], acc2);
            }
            if (c < NC) hw2s[node * NC + c] = (unsigned short)f2h_us(dc * acc2);
        }
    }
}

// ---- layer 2 pull-gather, fused b2/log_softmax -----------------------------

__global__ void k_gather2(const int* __restrict__ ns, const int2* __restrict__ bkt,
                          const unsigned short* __restrict__ hw2s,
                          const float* __restrict__ dinv, const float* __restrict__ b2,
                          float* __restrict__ out) {
    int t = blockIdx.x * 256 + threadIdx.x;
    int i = t >> 4, j = t & 15;
    int s = ns[i], e = ns[i + 1];
    float v;
    if (j < NC) {
        float acc = 0.f;
        int k = s;
        for (; k + 4 <= e; k += 4) {
            int2 e0 = bkt[k], e1 = bkt[k + 1], e2 = bkt[k + 2], e3 = bkt[k + 3];
            __half_raw h0; h0.x = hw2s[e0.x * NC + j];
            __half_raw h1; h1.x = hw2s[e1.x * NC + j];
            __half_raw h2; h2.x = hw2s[e2.x * NC + j];
            __half_raw h3; h3.x = hw2s[e3.x * NC + j];
            acc = fmaf(h2f_lo(e0.y), __half2float(*(__half*)&h0), acc);
            acc = fmaf(h2f_lo(e1.y), __half2float(*(__half*)&h1), acc);
            acc = fmaf(h2f_lo(e2.y), __half2float(*(__half*)&h2), acc);
            acc = fmaf(h2f_lo(e3.y), __half2float(*(__half*)&h3), acc);
        }
        for (; k < e; ++k) {
            int2 e0 = bkt[k];
            __half_raw h0; h0.x = hw2s[e0.x * NC + j];
            acc = fmaf(h2f_lo(e0.y), __half2float(*(__half*)&h0), acc);
        }
        { __half_raw hs; hs.x = hw2s[i * NC + j]; acc += __half2float(*(__half*)&hs); }
        v = fmaf(dinv[i], acc, b2[j]);
    } else {
        v = -1e30f;
    }
    float m = v;
    #pragma unroll
    for (int mask = 8; mask > 0; mask >>= 1) m = fmaxf(m, __shfl_xor(m, mask, HID));
    float ev = (j < NC) ? __expf(v - m) : 0.f;
    float ssum = ev;
    #pragma unroll
    for (int mask = 8; mask > 0; mask >>= 1) ssum += __shfl_xor(ssum, mask, HID);
    if (j < NC) out[(long)i * NC + j] = v - m - __logf(ssum);
}

// ---- launch -----------------------------------------------------------------

extern "C" void kernel_launch(void* const* d_in, const int* in_sizes, int n_in,
                              void* d_out, int out_size, void* d_ws, size_t ws_size,
                              hipStream_t stream) {
    const float* x  = (const float*)d_in[0];
    const int*   ei = (const int*)d_in[1];
    const float* ew = (const float*)d_in[2];
    const float* W1 = (const float*)d_in[3];
    const float* b1 = (const float*)d_in[4];
    const float* W2 = (const float*)d_in[5];
    const float* b2 = (const float*)d_in[6];
    float* out = (float*)d_out;

    const int* row = ei;
    const int* col = ei + NE;

    // workspace (words); xws overlays hist (dead after k_scatter)
    int*   hist   = (int*)d_ws;                    // NSEG*NB = 800,256
    int*   psum   = hist + NSEG * NB;              // NCH*NB  = 12,504
    int*   bstart = psum + NCH * NB;               // NB+1    = 1,564
    float* dinv   = (float*)(bstart + NB + 1);     // 100,000
    int*   ns     = (int*)(dinv + NN);             // 100,001
    size_t o = (size_t)(NSEG * NB) + NCH * NB + (NB + 1) + NN + (NN + 1);
    o = (o + 1) & ~(size_t)1;                      // 8B align for int2
    int2*  bkt    = (int2*)((int*)d_ws + o);       // NE int2 = 6,400,000 w
    unsigned short* hw2s = (unsigned short*)(bkt + NE);   // NN*NC halves = 500,000 w
    int2*  xws    = (int2*)hist;                   // NN*4 int2 = 800,000 w overlay
    // total ~= 7,914,326 words = 31.7 MB

    k_hist<<<NSEG, 256, 0, stream>>>(col, hist);
    k_psumA<<<dim3((NB + 255) / 256, NCH), 256, 0, stream>>>(hist, psum);
    k_psumB<<<(NB + 255) / 256, 256, 0, stream>>>(psum, bstart);
    k_scanBkt<<<1, 256, 0, stream>>>(bstart);
    k_applyC<<<dim3((NB + 255) / 256, NCH), 256, 0, stream>>>(hist, psum, bstart);
    k_scatter<<<NSEG, 256, 0, stream>>>(row, col, ew, hist, bkt);

    // 782 blocks x 4 waves x 2 tiles = 6256 >= 6250 tiles; block = 2 buckets
    k_xw<<<782, 256, 0, stream>>>(x, W1, bstart, bkt, dinv, xws);
    k_rg1<<<NB, 256, 0, stream>>>(bstart, bkt, dinv, ns, (const unsigned short*)xws,
                                  b1, W2, hw2s);
    k_gather2<<<(NN * 16) / 256, 256, 0, stream>>>(ns, bkt, hw2s, dinv, b2, out);
}

// Round 7
// 362.203 us; speedup vs baseline: 1.4133x; 1.0656x over previous
//
#include <hip/hip_runtime.h>
#include <hip/hip_fp16.h>

#define NN 100000
#define NE 3200000
#define FIN 300
#define HID 16
#define NC 10

#define NPB 64                  // nodes per bucket
#define NB 1563                 // ceil(NN / NPB)
#define NSEG 512                // edge segments
#define EPS (NE / NSEG)         // 6250 edges per segment
#define NCH 8                   // chunks for the seg-scan
#define SEGPC (NSEG / NCH)      // 64 segs per chunk
#define CAP 4096                // max bucket size (mean 2048, sd ~45)

#define NTILE 6250              // NN / 16 node-tiles for MFMA k_xw

typedef __fp16 h2 __attribute__((ext_vector_type(2)));
typedef __fp16 h8 __attribute__((ext_vector_type(8)));
typedef float f32x4 __attribute__((ext_vector_type(4)));

__device__ __forceinline__ float h2f_lo(int y) {
    __half_raw hr; hr.x = (unsigned short)(y & 0xFFFF);
    __half h; *(__half_raw*)&h = hr;
    return __half2float(h);
}
__device__ __forceinline__ int f2h_us(float f) {
    __half h = __float2half(f);
    return (int)(*(__half_raw*)&h).x;
}

// ---- phase 1: per-segment histogram over buckets ---------------------------

__launch_bounds__(512)
__global__ void k_hist(const int* __restrict__ col, int* __restrict__ hist) {
    __shared__ int bins[NB];
    int seg = blockIdx.x, tid = threadIdx.x;
    for (int i = tid; i < NB; i += 512) bins[i] = 0;
    __syncthreads();
    int base = seg * EPS;
    for (int k = tid; k < EPS; k += 512) atomicAdd(&bins[col[base + k] >> 6], 1);
    __syncthreads();
    for (int i = tid; i < NB; i += 512) hist[seg * NB + i] = bins[i];
}

// ---- phase 2: parallel scan of hist over segs ------------------------------

__global__ void k_psumA(const int* __restrict__ hist, int* __restrict__ psum) {
    int bin = blockIdx.x * 256 + threadIdx.x;
    int ch = blockIdx.y;
    if (bin >= NB) return;
    int s = 0;
    for (int seg = ch * SEGPC; seg < (ch + 1) * SEGPC; ++seg) s += hist[seg * NB + bin];
    psum[ch * NB + bin] = s;
}

__global__ void k_psumB(int* __restrict__ psum, int* __restrict__ bstart) {
    int bin = blockIdx.x * 256 + threadIdx.x;
    if (bin >= NB) return;
    int run = 0;
    #pragma unroll
    for (int ch = 0; ch < NCH; ++ch) {
        int v = psum[ch * NB + bin];
        psum[ch * NB + bin] = run;
        run += v;
    }
    bstart[bin] = run;
}

__global__ void k_scanBkt(int* __restrict__ bstart) {
    __shared__ int lsum[256];
    int t = threadIdx.x;
    const int M = (NB + 255) / 256;   // 7
    int base = t * M;
    int s = 0;
    for (int q = 0; q < M; ++q) { int i = base + q; if (i < NB) s += bstart[i]; }
    lsum[t] = s; __syncthreads();
    for (int off = 1; off < 256; off <<= 1) {
        int add = (t >= off) ? lsum[t - off] : 0;
        __syncthreads(); lsum[t] += add; __syncthreads();
    }
    int run = (t > 0) ? lsum[t - 1] : 0;
    for (int q = 0; q < M; ++q) {
        int i = base + q;
        if (i < NB) { int v = bstart[i]; bstart[i] = run; run += v; }
    }
    if (t == 255) bstart[NB] = run;   // = NE
}

__global__ void k_applyC(int* __restrict__ hist, const int* __restrict__ psum,
                         const int* __restrict__ bstart) {
    int bin = blockIdx.x * 256 + threadIdx.x;
    int ch = blockIdx.y;
    if (bin >= NB) return;
    int run = bstart[bin] + psum[ch * NB + bin];
    for (int seg = ch * SEGPC; seg < (ch + 1) * SEGPC; ++seg) {
        int idx = seg * NB + bin;
        int v = hist[idx];
        hist[idx] = run;
        run += v;
    }
}

// ---- phase 3: LDS-sorted scatter, coalesced int2 writes --------------------
// record: .x = row | (col&63)<<17 ; .y = w_half | bin<<16 (bin bits scrubbed later)
// 512 threads: LDS caps at 2 blocks/CU either way; 8 waves/block doubles
// waves/CU (8 -> 16) for the latency-bound LDS-atomic + scatter-write phases.
// NO global atomics (round-5 lesson: memory-side on MI355X, +120us).

__launch_bounds__(512)
__global__ void k_scatter(const int* __restrict__ row, const int* __restrict__ col,
                          const float* __restrict__ w, const int* __restrict__ hist,
                          int2* __restrict__ bkt) {
    __shared__ int bins[NB];
    __shared__ int cur[NB];
    __shared__ int lsum[512];
    __shared__ int2 sdata[EPS];
    int seg = blockIdx.x, tid = threadIdx.x;
    for (int i = tid; i < NB; i += 512) bins[i] = 0;
    __syncthreads();
    int base = seg * EPS;
    for (int k = tid; k < EPS; k += 512) atomicAdd(&bins[col[base + k] >> 6], 1);
    __syncthreads();
    // block exclusive scan of bins
    const int M = (NB + 511) / 512;   // 4
    int lbase = tid * M;
    int s = 0;
    for (int q = 0; q < M; ++q) { int i = lbase + q; if (i < NB) s += bins[i]; }
    lsum[tid] = s; __syncthreads();
    for (int off = 1; off < 512; off <<= 1) {
        int add = (tid >= off) ? lsum[tid - off] : 0;
        __syncthreads(); lsum[tid] += add; __syncthreads();
    }
    int run = (tid > 0) ? lsum[tid - 1] : 0;
    for (int q = 0; q < M; ++q) {
        int i = lbase + q;
        if (i < NB) { int v = bins[i]; bins[i] = run; cur[i] = run; run += v; }
    }
    __syncthreads();
    // place into LDS sorted by bin
    for (int k = tid; k < EPS; k += 512) {
        int e = base + k;
        int r = row[e], c = col[e];
        int bin = c >> 6;
        int pos = atomicAdd(&cur[bin], 1);
        sdata[pos] = make_int2(r | ((c & 63) << 17), f2h_us(w[e]) | (bin << 16));
    }
    __syncthreads();
    // bins[bin] := global_start(seg,bin) - lds_start(bin)
    for (int i = tid; i < NB; i += 512) bins[i] = hist[seg * NB + i] - bins[i];
    __syncthreads();
    for (int j = tid; j < EPS; j += 512) {
        int2 d = sdata[j];
        int bin = ((unsigned)d.y) >> 16;
        bkt[bins[bin] + j] = d;
    }
}

// ---- x @ W1 via MFMA + fused per-bucket wdeg/dinv --------------------------
// Block = 1 bucket = 64 nodes = 4 MFMA tiles (1 per wave). Grid 1563 blocks
// (~6/CU) for latency hiding. Phase A: stream the bucket's edges (bkt is
// bucket-contiguous after scatter), LDS-atomicAdd wdeg[64], write dinv[].
// Phase B: 16x16x32 f16 MFMA over K=320 (zero-padded), C-write scaled by dinv.

__launch_bounds__(256)
__global__ void k_xw(const float* __restrict__ x, const float* __restrict__ W1,
                     const int* __restrict__ bstart, const int2* __restrict__ bkt,
                     float* __restrict__ dinv, int2* __restrict__ xws) {
    __shared__ h8 bfrag[10][64];        // 10 KB, frag-ordered W1 in f16
    __shared__ float wd[NPB];
    int tid = threadIdx.x;
    int b = blockIdx.x;                 // bucket
    if (tid < NPB) wd[tid] = 1.0f;      // self-loop weight
    // stage + convert W1: entry (s,l): col=l&15, k = 32s + 8*(l>>4) + j
    for (int e2 = tid; e2 < 640; e2 += 256) {
        int s = e2 >> 6, l = e2 & 63;
        int g = l >> 4, c = l & 15;
        int kb = 32 * s + 8 * g;
        float f[8];
        #pragma unroll
        for (int j = 0; j < 8; ++j) {
            int k = kb + j;
            f[j] = (k < FIN) ? W1[k * HID + c] : 0.f;
        }
        h2 q0 = __builtin_amdgcn_cvt_pkrtz(f[0], f[1]);
        h2 q1 = __builtin_amdgcn_cvt_pkrtz(f[2], f[3]);
        h2 q2 = __builtin_amdgcn_cvt_pkrtz(f[4], f[5]);
        h2 q3 = __builtin_amdgcn_cvt_pkrtz(f[6], f[7]);
        h8 v;
        v[0] = q0[0]; v[1] = q0[1]; v[2] = q1[0]; v[3] = q1[1];
        v[4] = q2[0]; v[5] = q2[1]; v[6] = q3[0]; v[7] = q3[1];
        bfrag[s][l] = v;
    }
    __syncthreads();
    // phase A: wdeg for bucket b (all records here have bin == b)
    int es = bstart[b], ee = bstart[b + 1];
    for (int k = es + tid; k < ee; k += 256) {
        int2 d = bkt[k];
        atomicAdd(&wd[(d.x >> 17) & 63], h2f_lo(d.y));
    }
    __syncthreads();
    if (tid < NPB) {
        int node = b * NPB + tid;
        float di = rsqrtf(wd[tid]);
        wd[tid] = di;
        if (node < NN) dinv[node] = di;
    }
    __syncthreads();
    // phase B: MFMA, 1 tile per wave
    int widx = tid >> 6, lane = tid & 63;
    int g = lane >> 4, rr = lane & 15;
    int tile = b * 4 + widx;
    unsigned short* op = (unsigned short*)xws;
    if (tile < NTILE) {
        int n0 = tile * 16;
        const float* xrow = x + (long)(n0 + rr) * FIN;
        f32x4 acc = {0.f, 0.f, 0.f, 0.f};
        #pragma unroll
        for (int s = 0; s < 9; ++s) {
            int k0 = 32 * s + 8 * g;
            f32x4 u0 = *(const f32x4*)(xrow + k0);
            f32x4 u1 = *(const f32x4*)(xrow + k0 + 4);
            h2 p0 = __builtin_amdgcn_cvt_pkrtz(u0[0], u0[1]);
            h2 p1 = __builtin_amdgcn_cvt_pkrtz(u0[2], u0[3]);
            h2 p2 = __builtin_amdgcn_cvt_pkrtz(u1[0], u1[1]);
            h2 p3 = __builtin_amdgcn_cvt_pkrtz(u1[2], u1[3]);
            h8 a;
            a[0] = p0[0]; a[1] = p0[1]; a[2] = p1[0]; a[3] = p1[1];
            a[4] = p2[0]; a[5] = p2[1]; a[6] = p3[0]; a[7] = p3[1];
            acc = __builtin_amdgcn_mfma_f32_16x16x32_f16(a, bfrag[s][lane], acc, 0, 0, 0);
        }
        {   // K tail: k 288..299 valid, 300..319 zero
            int k0 = 288 + 8 * g;
            f32x4 z = {0.f, 0.f, 0.f, 0.f};
            f32x4 u0 = (g < 2) ? *(const f32x4*)(xrow + k0) : z;
            f32x4 u1 = (g == 0) ? *(const f32x4*)(xrow + k0 + 4) : z;
            h2 p0 = __builtin_amdgcn_cvt_pkrtz(u0[0], u0[1]);
            h2 p1 = __builtin_amdgcn_cvt_pkrtz(u0[2], u0[3]);
            h2 p2 = __builtin_amdgcn_cvt_pkrtz(u1[0], u1[1]);
            h2 p3 = __builtin_amdgcn_cvt_pkrtz(u1[2], u1[3]);
            h8 a;
            a[0] = p0[0]; a[1] = p0[1]; a[2] = p1[0]; a[3] = p1[1];
            a[4] = p2[0]; a[5] = p2[1]; a[6] = p3[0]; a[7] = p3[1];
            acc = __builtin_amdgcn_mfma_f32_16x16x32_f16(a, bfrag[9][lane], acc, 0, 0, 0);
        }
        // C/D: col = lane&15 (=rr), row-in-tile = g*4 + r2
        #pragma unroll
        for (int r2 = 0; r2 < 4; ++r2) {
            int node = n0 + g * 4 + r2;
            float di = wd[widx * 16 + g * 4 + r2];
            op[(long)node * HID + rr] = (unsigned short)f2h_us(di * acc[r2]);
        }
    }
}

// ---- fused refine + layer-1 gather -----------------------------------------
// Per bucket: count/scan/sort edges into LDS (node order), emit PACKED 4-byte
// records (src:17 | w_fp16_sign-dropped:15) for k_gather2, then gather layer 1
// straight from LDS, fused b1/relu/@W2, fp16 store.

__launch_bounds__(256)
__global__ void k_rg1(const int* __restrict__ bstart, const int2* __restrict__ bkt,
                      const float* __restrict__ dinv, int* __restrict__ ns,
                      const unsigned short* __restrict__ xwsh,
                      const float* __restrict__ b1, const float* __restrict__ W2,
                      unsigned short* __restrict__ hw2s, int* __restrict__ pbkt) {
    __shared__ int cnt[NPB];
    __shared__ int cur[NPB];
    __shared__ int off[NPB + 1];
    __shared__ int2 sorted[CAP];
    __shared__ float w2s[HID * NC];
    __shared__ float b1s[HID];
    int b = blockIdx.x, tid = threadIdx.x;
    if (tid < HID * NC) w2s[tid] = W2[tid];
    if (tid < HID) b1s[tid] = b1[tid];
    int s = bstart[b], e = bstart[b + 1];
    int size = e - s; if (size > CAP) size = CAP;   // 45-sigma guard, never hit
    if (tid < NPB) cnt[tid] = 0;
    __syncthreads();
    for (int k = tid; k < size; k += 256) {
        int2 d = bkt[s + k];
        atomicAdd(&cnt[(d.x >> 17) & 63], 1);
    }
    __syncthreads();
    int v = (tid < NPB) ? cnt[tid] : 0;
    for (int o = 1; o < NPB; o <<= 1) {
        int add = (tid >= o && tid < NPB) ? cnt[tid - o] : 0;
        __syncthreads();
        if (tid < NPB) cnt[tid] += add;
        __syncthreads();
    }
    if (tid < NPB) {
        int excl = cnt[tid] - v;
        cur[tid] = excl;
        off[tid] = excl;
        int node = b * NPB + tid;
        if (node < NN) ns[node] = s + excl;
    }
    if (tid == 0) off[NPB] = size;
    if (b == NB - 1 && tid == 0) ns[NN] = e;
    __syncthreads();
    for (int k = tid; k < size; k += 256) {
        int2 d = bkt[s + k];
        int cl = (d.x >> 17) & 63;
        int pos = atomicAdd(&cur[cl], 1);
        sorted[pos] = make_int2(d.x & 0x1FFFF, d.y & 0xFFFF);
    }
    __syncthreads();
    // packed node-sorted edges for k_gather2: src | whalf<<17 (w >= 0)
    for (int k = tid; k < size; k += 256) {
        int2 d = sorted[k];
        pbkt[s + k] = d.x | (d.y << 17);
    }
    // layer-1 gather from LDS
    int c = tid & 15, g = tid >> 4;   // g in 0..15
    #pragma unroll 1
    for (int q = 0; q < 4; ++q) {
        int nl = g + 16 * q;
        int node = b * NPB + nl;
        int o0 = off[nl], o1 = off[nl + 1];
        float acc = 0.f;
        int k = o0;
        for (; k + 4 <= o1; k += 4) {
            int2 e0 = sorted[k], e1 = sorted[k + 1], e2 = sorted[k + 2], e3 = sorted[k + 3];
            __half_raw h0; h0.x = xwsh[e0.x * HID + c];
            __half_raw h1; h1.x = xwsh[e1.x * HID + c];
            __half_raw h2; h2.x = xwsh[e2.x * HID + c];
            __half_raw h3; h3.x = xwsh[e3.x * HID + c];
            acc = fmaf(h2f_lo(e0.y), __half2float(*(__half*)&h0), acc);
            acc = fmaf(h2f_lo(e1.y), __half2float(*(__half*)&h1), acc);
            acc = fmaf(h2f_lo(e2.y), __half2float(*(__half*)&h2), acc);
            acc = fmaf(h2f_lo(e3.y), __half2float(*(__half*)&h3), acc);
        }
        for (; k < o1; ++k) {
            int2 e0 = sorted[k];
            __half_raw h0; h0.x = xwsh[e0.x * HID + c];
            acc = fmaf(h2f_lo(e0.y), __half2float(*(__half*)&h0), acc);
        }
        if (node < NN) {
            { __half_raw hs; hs.x = xwsh[node * HID + c]; acc += __half2float(*(__half*)&hs); }
            float dc = dinv[node];
            float h = fmaxf(fmaf(dc, acc, b1s[c]), 0.f);
            float acc2 = 0.f;
            int jj = (c < NC) ? c : 0;
            #pragma unroll
            for (int k2 = 0; k2 < HID; ++k2) {
                float hk = __shfl(h, k2, HID);
                acc2 = fmaf(hk, w2s[k2 * NC + jj], acc2);
            }
            if (c < NC) hw2s[node * NC + c] = (unsigned short)f2h_us(dc * acc2);
        }
    }
}

// ---- layer 2 pull-gather (packed 4-B edges), fused b2/log_softmax ----------

__global__ void k_gather2(const int* __restrict__ ns, const int* __restrict__ pbkt,
                          const unsigned short* __restrict__ hw2s,
                          const float* __restrict__ dinv, const float* __restrict__ b2,
                          float* __restrict__ out) {
    int t = blockIdx.x * 256 + threadIdx.x;
    int i = t >> 4, j = t & 15;
    int s = ns[i], e = ns[i + 1];
    float v;
    if (j < NC) {
        float acc = 0.f;
        int k = s;
        for (; k + 4 <= e; k += 4) {
            int p0 = pbkt[k], p1 = pbkt[k + 1], p2 = pbkt[k + 2], p3 = pbkt[k + 3];
            __half_raw h0; h0.x = hw2s[(p0 & 0x1FFFF) * NC + j];
            __half_raw h1; h1.x = hw2s[(p1 & 0x1FFFF) * NC + j];
            __half_raw h2; h2.x = hw2s[(p2 & 0x1FFFF) * NC + j];
            __half_raw h3; h3.x = hw2s[(p3 & 0x1FFFF) * NC + j];
            acc = fmaf(h2f_lo(((unsigned)p0) >> 17), __half2float(*(__half*)&h0), acc);
            acc = fmaf(h2f_lo(((unsigned)p1) >> 17), __half2float(*(__half*)&h1), acc);
            acc = fmaf(h2f_lo(((unsigned)p2) >> 17), __half2float(*(__half*)&h2), acc);
            acc = fmaf(h2f_lo(((unsigned)p3) >> 17), __half2float(*(__half*)&h3), acc);
        }
        for (; k < e; ++k) {
            int p0 = pbkt[k];
            __half_raw h0; h0.x = hw2s[(p0 & 0x1FFFF) * NC + j];
            acc = fmaf(h2f_lo(((unsigned)p0) >> 17), __half2float(*(__half*)&h0), acc);
        }
        { __half_raw hs; hs.x = hw2s[i * NC + j]; acc += __half2float(*(__half*)&hs); }
        v = fmaf(dinv[i], acc, b2[j]);
    } else {
        v = -1e30f;
    }
    float m = v;
    #pragma unroll
    for (int mask = 8; mask > 0; mask >>= 1) m = fmaxf(m, __shfl_xor(m, mask, HID));
    float ev = (j < NC) ? __expf(v - m) : 0.f;
    float ssum = ev;
    #pragma unroll
    for (int mask = 8; mask > 0; mask >>= 1) ssum += __shfl_xor(ssum, mask, HID);
    if (j < NC) out[(long)i * NC + j] = v - m - __logf(ssum);
}

// ---- launch -----------------------------------------------------------------

extern "C" void kernel_launch(void* const* d_in, const int* in_sizes, int n_in,
                              void* d_out, int out_size, void* d_ws, size_t ws_size,
                              hipStream_t stream) {
    const float* x  = (const float*)d_in[0];
    const int*   ei = (const int*)d_in[1];
    const float* ew = (const float*)d_in[2];
    const float* W1 = (const float*)d_in[3];
    const float* b1 = (const float*)d_in[4];
    const float* W2 = (const float*)d_in[5];
    const float* b2 = (const float*)d_in[6];
    float* out = (float*)d_out;

    const int* row = ei;
    const int* col = ei + NE;

    // workspace (words); xws overlays hist (dead after k_scatter)
    int*   hist   = (int*)d_ws;                    // NSEG*NB = 800,256
    int*   psum   = hist + NSEG * NB;              // NCH*NB  = 12,504
    int*   bstart = psum + NCH * NB;               // NB+1    = 1,564
    float* dinv   = (float*)(bstart + NB + 1);     // 100,000
    int*   ns     = (int*)(dinv + NN);             // 100,001
    size_t o = (size_t)(NSEG * NB) + NCH * NB + (NB + 1) + NN + (NN + 1);
    o = (o + 1) & ~(size_t)1;                      // 8B align for int2
    int2*  bkt    = (int2*)((int*)d_ws + o);       // NE int2 = 6,400,000 w
    unsigned short* hw2s = (unsigned short*)(bkt + NE);   // NN*NC halves = 500,000 w
    int*   pbkt   = (int*)(hw2s + (size_t)NN * NC);       // NE words = 3,200,000 w
    int2*  xws    = (int2*)hist;                   // NN*4 int2 = 800,000 w overlay
    // total ~= 11.1 M words = 44.5 MB (ws is 480 MB)

    k_hist<<<NSEG, 512, 0, stream>>>(col, hist);
    k_psumA<<<dim3((NB + 255) / 256, NCH), 256, 0, stream>>>(hist, psum);
    k_psumB<<<(NB + 255) / 256, 256, 0, stream>>>(psum, bstart);
    k_scanBkt<<<1, 256, 0, stream>>>(bstart);
    k_applyC<<<dim3((NB + 255) / 256, NCH), 256, 0, stream>>>(hist, psum, bstart);
    k_scatter<<<NSEG, 512, 0, stream>>>(row, col, ew, hist, bkt);

    // 1563 blocks: block = bucket; 4 waves = 4 MFMA tiles = 64 nodes
    k_xw<<<NB, 256, 0, stream>>>(x, W1, bstart, bkt, dinv, xws);
    k_rg1<<<NB, 256, 0, stream>>>(bstart, bkt, dinv, ns, (const unsigned short*)xws,
                                  b1, W2, hw2s, pbkt);
    k_gather2<<<(NN * 16) / 256, 256, 0, stream>>>(ns, pbkt, hw2s, dinv, b2, out);
}

// Round 8
// 361.568 us; speedup vs baseline: 1.4158x; 1.0018x over previous
//
#include <hip/hip_runtime.h>
#include <hip/hip_fp16.h>

#define NN 100000
#define NE 3200000
#define FIN 300
#define HID 16
#define NC 10

#define NPB 64                  // nodes per bucket
#define NB 1563                 // ceil(NN / NPB)
#define NSEG 512                // edge segments
#define EPS (NE / NSEG)         // 6250 edges per segment
#define NCH 8                   // chunks for the seg-scan
#define SEGPC (NSEG / NCH)      // 64 segs per chunk
#define CAP 4096                // max bucket size (mean 2048, sd ~45)

#define NTILE 6250              // NN / 16 node-tiles for MFMA k_xw

typedef __fp16 h2 __attribute__((ext_vector_type(2)));
typedef __fp16 h8 __attribute__((ext_vector_type(8)));
typedef float f32x4 __attribute__((ext_vector_type(4)));

__device__ __forceinline__ float h2f_lo(int y) {
    __half_raw hr; hr.x = (unsigned short)(y & 0xFFFF);
    __half h; *(__half_raw*)&h = hr;
    return __half2float(h);
}
__device__ __forceinline__ int f2h_us(float f) {
    __half h = __float2half(f);
    return (int)(*(__half_raw*)&h).x;
}

// pack 8 f32 (two f32x4) -> h8 via cvt_pkrtz, no elementwise movs
__device__ __forceinline__ h8 pack8(f32x4 u0, f32x4 u1) {
    union { h2 p; unsigned u; } c0, c1, c2, c3;
    c0.p = __builtin_amdgcn_cvt_pkrtz(u0[0], u0[1]);
    c1.p = __builtin_amdgcn_cvt_pkrtz(u0[2], u0[3]);
    c2.p = __builtin_amdgcn_cvt_pkrtz(u1[0], u1[1]);
    c3.p = __builtin_amdgcn_cvt_pkrtz(u1[2], u1[3]);
    union { uint4 u; h8 h; } r;
    r.u = make_uint4(c0.u, c1.u, c2.u, c3.u);
    return r.h;
}

// block exclusive scan via wave shuffle + cross-wave LDS (2 barriers)
__device__ __forceinline__ int blockScanExcl(int v, int tid, int* wsum) {
    int incl = v;
    #pragma unroll
    for (int off = 1; off < 64; off <<= 1) {
        int t2 = __shfl_up(incl, off, 64);
        if ((tid & 63) >= off) incl += t2;
    }
    int wid = tid >> 6;
    if ((tid & 63) == 63) wsum[wid] = incl;
    __syncthreads();
    int wof = 0;
    for (int w2 = 0; w2 < wid; ++w2) wof += wsum[w2];
    __syncthreads();
    return wof + incl - v;
}

// ---- phase 1: per-segment histogram over buckets ---------------------------

__launch_bounds__(512)
__global__ void k_hist(const int* __restrict__ col, int* __restrict__ hist) {
    __shared__ int bins[NB];
    int seg = blockIdx.x, tid = threadIdx.x;
    for (int i = tid; i < NB; i += 512) bins[i] = 0;
    __syncthreads();
    int base = seg * EPS;
    for (int k = tid; k < EPS; k += 512) atomicAdd(&bins[col[base + k] >> 6], 1);
    __syncthreads();
    for (int i = tid; i < NB; i += 512) hist[seg * NB + i] = bins[i];
}

// ---- phase 2: parallel scan of hist over segs ------------------------------

__global__ void k_psumA(const int* __restrict__ hist, int* __restrict__ psum) {
    int bin = blockIdx.x * 256 + threadIdx.x;
    int ch = blockIdx.y;
    if (bin >= NB) return;
    int s = 0;
    for (int seg = ch * SEGPC; seg < (ch + 1) * SEGPC; ++seg) s += hist[seg * NB + bin];
    psum[ch * NB + bin] = s;
}

// fused psumB + scanBkt: single block; per-bin chunk-scan then block scan
__global__ void k_scanAll(int* __restrict__ psum, int* __restrict__ bstart) {
    __shared__ int wsum[4];
    int t = threadIdx.x;
    const int M = (NB + 255) / 256;   // 7
    int base = t * M;
    int tot[M];
    int s = 0;
    #pragma unroll
    for (int q = 0; q < M; ++q) {
        int bin = base + q;
        int bt = 0;
        if (bin < NB) {
            int run = 0;
            #pragma unroll
            for (int ch = 0; ch < NCH; ++ch) {
                int v = psum[ch * NB + bin];
                psum[ch * NB + bin] = run;
                run += v;
            }
            bt = run;
        }
        tot[q] = bt;
        s += bt;
    }
    int run = blockScanExcl(s, t, wsum);
    #pragma unroll
    for (int q = 0; q < M; ++q) {
        int bin = base + q;
        if (bin < NB) { bstart[bin] = run; run += tot[q]; }
    }
    if (t == 255) bstart[NB] = run;   // = NE
}

__global__ void k_applyC(int* __restrict__ hist, const int* __restrict__ psum,
                         const int* __restrict__ bstart) {
    int bin = blockIdx.x * 256 + threadIdx.x;
    int ch = blockIdx.y;
    if (bin >= NB) return;
    int run = bstart[bin] + psum[ch * NB + bin];
    for (int seg = ch * SEGPC; seg < (ch + 1) * SEGPC; ++seg) {
        int idx = seg * NB + bin;
        int v = hist[idx];
        hist[idx] = run;
        run += v;
    }
}

// ---- phase 3: LDS-sorted scatter, coalesced int2 writes --------------------
// record: .x = row | (col&63)<<17 ; .y = w_half | bin<<16 (bin bits scrubbed later)
// NO global atomics (round-5 lesson: memory-side on MI355X, +120us).

__launch_bounds__(512)
__global__ void k_scatter(const int* __restrict__ row, const int* __restrict__ col,
                          const float* __restrict__ w, const int* __restrict__ hist,
                          int2* __restrict__ bkt) {
    __shared__ int bins[NB];
    __shared__ int cur[NB];
    __shared__ int wsum[8];
    __shared__ int2 sdata[EPS];
    int seg = blockIdx.x, tid = threadIdx.x;
    for (int i = tid; i < NB; i += 512) bins[i] = 0;
    __syncthreads();
    int base = seg * EPS;
    for (int k = tid; k < EPS; k += 512) atomicAdd(&bins[col[base + k] >> 6], 1);
    __syncthreads();
    // block exclusive scan of bins (shuffle-based, 2 barriers)
    const int M = (NB + 511) / 512;   // 4
    int lbase = tid * M;
    int s = 0;
    #pragma unroll
    for (int q = 0; q < M; ++q) { int i = lbase + q; if (i < NB) s += bins[i]; }
    int run = blockScanExcl(s, tid, wsum);
    #pragma unroll
    for (int q = 0; q < M; ++q) {
        int i = lbase + q;
        if (i < NB) { int v = bins[i]; bins[i] = run; cur[i] = run; run += v; }
    }
    __syncthreads();
    // place into LDS sorted by bin
    for (int k = tid; k < EPS; k += 512) {
        int e = base + k;
        int r = row[e], c = col[e];
        int bin = c >> 6;
        int pos = atomicAdd(&cur[bin], 1);
        sdata[pos] = make_int2(r | ((c & 63) << 17), f2h_us(w[e]) | (bin << 16));
    }
    __syncthreads();
    // bins[bin] := global_start(seg,bin) - lds_start(bin)
    for (int i = tid; i < NB; i += 512) bins[i] = hist[seg * NB + i] - bins[i];
    __syncthreads();
    for (int j = tid; j < EPS; j += 512) {
        int2 d = sdata[j];
        int bin = ((unsigned)d.y) >> 16;
        bkt[bins[bin] + j] = d;
    }
}

// ---- x @ W1 via MFMA + fused per-bucket wdeg/dinv --------------------------
// Block = 1 bucket = 64 nodes = 4 MFMA tiles (1 per wave). Phase A: stream the
// bucket's edges, LDS-atomicAdd wdeg[64], write dinv[]. Phase B: 16x16x32 f16
// MFMA over K=320 (zero-padded), C-write scaled by dinv.

__launch_bounds__(256)
__global__ void k_xw(const float* __restrict__ x, const float* __restrict__ W1,
                     const int* __restrict__ bstart, const int2* __restrict__ bkt,
                     float* __restrict__ dinv, int2* __restrict__ xws) {
    __shared__ h8 bfrag[10][64];        // 10 KB, frag-ordered W1 in f16
    __shared__ float wd[NPB];
    int tid = threadIdx.x;
    int b = blockIdx.x;                 // bucket
    if (tid < NPB) wd[tid] = 1.0f;      // self-loop weight
    // stage + convert W1: entry (s,l): col=l&15, k = 32s + 8*(l>>4) + j
    for (int e2 = tid; e2 < 640; e2 += 256) {
        int s = e2 >> 6, l = e2 & 63;
        int g = l >> 4, c = l & 15;
        int kb = 32 * s + 8 * g;
        f32x4 u0, u1;
        #pragma unroll
        for (int j = 0; j < 4; ++j) {
            int k = kb + j;
            u0[j] = (k < FIN) ? W1[k * HID + c] : 0.f;
        }
        #pragma unroll
        for (int j = 0; j < 4; ++j) {
            int k = kb + 4 + j;
            u1[j] = (k < FIN) ? W1[k * HID + c] : 0.f;
        }
        bfrag[s][l] = pack8(u0, u1);
    }
    __syncthreads();
    // phase A: wdeg for bucket b (all records here have bin == b)
    int es = bstart[b], ee = bstart[b + 1];
    for (int k = es + tid; k < ee; k += 256) {
        int2 d = bkt[k];
        atomicAdd(&wd[(d.x >> 17) & 63], h2f_lo(d.y));
    }
    __syncthreads();
    if (tid < NPB) {
        int node = b * NPB + tid;
        float di = rsqrtf(wd[tid]);
        wd[tid] = di;
        if (node < NN) dinv[node] = di;
    }
    __syncthreads();
    // phase B: MFMA, 1 tile per wave
    int widx = tid >> 6, lane = tid & 63;
    int g = lane >> 4, rr = lane & 15;
    int tile = b * 4 + widx;
    unsigned short* op = (unsigned short*)xws;
    if (tile < NTILE) {
        int n0 = tile * 16;
        const float* xrow = x + (long)(n0 + rr) * FIN;
        f32x4 acc = {0.f, 0.f, 0.f, 0.f};
        #pragma unroll
        for (int s = 0; s < 9; ++s) {
            int k0 = 32 * s + 8 * g;
            f32x4 u0 = *(const f32x4*)(xrow + k0);
            f32x4 u1 = *(const f32x4*)(xrow + k0 + 4);
            acc = __builtin_amdgcn_mfma_f32_16x16x32_f16(pack8(u0, u1), bfrag[s][lane], acc, 0, 0, 0);
        }
        {   // K tail: k 288..299 valid, 300..319 zero
            int k0 = 288 + 8 * g;
            f32x4 z = {0.f, 0.f, 0.f, 0.f};
            f32x4 u0 = (g < 2) ? *(const f32x4*)(xrow + k0) : z;
            f32x4 u1 = (g == 0) ? *(const f32x4*)(xrow + k0 + 4) : z;
            acc = __builtin_amdgcn_mfma_f32_16x16x32_f16(pack8(u0, u1), bfrag[9][lane], acc, 0, 0, 0);
        }
        // C/D: col = lane&15 (=rr), row-in-tile = g*4 + r2
        #pragma unroll
        for (int r2 = 0; r2 < 4; ++r2) {
            int node = n0 + g * 4 + r2;
            float di = wd[widx * 16 + g * 4 + r2];
            op[(long)node * HID + rr] = (unsigned short)f2h_us(di * acc[r2]);
        }
    }
}

// ---- fused refine + layer-1 gather -----------------------------------------
// Per bucket: count/scan/sort edges into LDS (node order), emit PACKED 4-byte
// records (src:17 | w_fp16:15) for k_gather2, then gather layer 1 straight
// from LDS, fused b1/relu/@W2, fp16 store.

__launch_bounds__(256)
__global__ void k_rg1(const int* __restrict__ bstart, const int2* __restrict__ bkt,
                      const float* __restrict__ dinv, int* __restrict__ ns,
                      const unsigned short* __restrict__ xwsh,
                      const float* __restrict__ b1, const float* __restrict__ W2,
                      unsigned short* __restrict__ hw2s, int* __restrict__ pbkt) {
    __shared__ int cnt[NPB];
    __shared__ int cur[NPB];
    __shared__ int off[NPB + 1];
    __shared__ int2 sorted[CAP];
    __shared__ float w2s[HID * NC];
    __shared__ float b1s[HID];
    int b = blockIdx.x, tid = threadIdx.x;
    if (tid < HID * NC) w2s[tid] = W2[tid];
    if (tid < HID) b1s[tid] = b1[tid];
    int s = bstart[b], e = bstart[b + 1];
    int size = e - s; if (size > CAP) size = CAP;   // 45-sigma guard, never hit
    if (tid < NPB) cnt[tid] = 0;
    __syncthreads();
    for (int k = tid; k < size; k += 256) {
        int2 d = bkt[s + k];
        atomicAdd(&cnt[(d.x >> 17) & 63], 1);
    }
    __syncthreads();
    // 64-class exclusive scan: single wave (threads 0..63), shuffle-based
    if (tid < NPB) {
        int vcl = cnt[tid];
        int incl = vcl;
        #pragma unroll
        for (int o = 1; o < 64; o <<= 1) {
            int t2 = __shfl_up(incl, o, 64);
            if (tid >= o) incl += t2;
        }
        int excl = incl - vcl;
        cur[tid] = excl;
        off[tid] = excl;
        int node = b * NPB + tid;
        if (node < NN) ns[node] = s + excl;
        if (tid == 0) off[NPB] = size;
    }
    if (b == NB - 1 && tid == 0) ns[NN] = e;
    __syncthreads();
    for (int k = tid; k < size; k += 256) {
        int2 d = bkt[s + k];
        int cl = (d.x >> 17) & 63;
        int pos = atomicAdd(&cur[cl], 1);
        sorted[pos] = make_int2(d.x & 0x1FFFF, d.y & 0xFFFF);
    }
    __syncthreads();
    // packed node-sorted edges for k_gather2: src | whalf<<17 (w >= 0)
    for (int k = tid; k < size; k += 256) {
        int2 d = sorted[k];
        pbkt[s + k] = d.x | (d.y << 17);
    }
    // layer-1 gather from LDS
    int c = tid & 15, g = tid >> 4;   // g in 0..15
    #pragma unroll 1
    for (int q = 0; q < 4; ++q) {
        int nl = g + 16 * q;
        int node = b * NPB + nl;
        int o0 = off[nl], o1 = off[nl + 1];
        float acc = 0.f;
        int k = o0;
        for (; k + 4 <= o1; k += 4) {
            int2 e0 = sorted[k], e1 = sorted[k + 1], e2 = sorted[k + 2], e3 = sorted[k + 3];
            __half_raw h0; h0.x = xwsh[e0.x * HID + c];
            __half_raw h1; h1.x = xwsh[e1.x * HID + c];
            __half_raw h2; h2.x = xwsh[e2.x * HID + c];
            __half_raw h3; h3.x = xwsh[e3.x * HID + c];
            acc = fmaf(h2f_lo(e0.y), __half2float(*(__half*)&h0), acc);
            acc = fmaf(h2f_lo(e1.y), __half2float(*(__half*)&h1), acc);
            acc = fmaf(h2f_lo(e2.y), __half2float(*(__half*)&h2), acc);
            acc = fmaf(h2f_lo(e3.y), __half2float(*(__half*)&h3), acc);
        }
        for (; k < o1; ++k) {
            int2 e0 = sorted[k];
            __half_raw h0; h0.x = xwsh[e0.x * HID + c];
            acc = fmaf(h2f_lo(e0.y), __half2float(*(__half*)&h0), acc);
        }
        if (node < NN) {
            { __half_raw hs; hs.x = xwsh[node * HID + c]; acc += __half2float(*(__half*)&hs); }
            float dc = dinv[node];
            float h = fmaxf(fmaf(dc, acc, b1s[c]), 0.f);
            float acc2 = 0.f;
            int jj = (c < NC) ? c : 0;
            #pragma unroll
            for (int k2 = 0; k2 < HID; ++k2) {
                float hk = __shfl(h, k2, HID);
                acc2 = fmaf(hk, w2s[k2 * NC + jj], acc2);
            }
            if (c < NC) hw2s[node * NC + c] = (unsigned short)f2h_us(dc * acc2);
        }
    }
}

// ---- layer 2 pull-gather (packed 4-B edges, int4 loads), b2/log_softmax ----

__global__ void k_gather2(const int* __restrict__ ns, const int* __restrict__ pbkt,
                          const unsigned short* __restrict__ hw2s,
                          const float* __restrict__ dinv, const float* __restrict__ b2,
                          float* __restrict__ out) {
    int t = blockIdx.x * 256 + threadIdx.x;
    int i = t >> 4, j = t & 15;
    int s = ns[i], e = ns[i + 1];
    float v;
    if (j < NC) {
        float acc = 0.f;
        int k = s;
        int ka = (s + 3) & ~3; if (ka > e) ka = e;
        for (; k < ka; ++k) {
            int p0 = pbkt[k];
            __half_raw h0; h0.x = hw2s[(p0 & 0x1FFFF) * NC + j];
            acc = fmaf(h2f_lo(((unsigned)p0) >> 17), __half2float(*(__half*)&h0), acc);
        }
        #pragma unroll 2
        for (; k + 4 <= e; k += 4) {
            int4 p = *(const int4*)(pbkt + k);
            __half_raw h0; h0.x = hw2s[(p.x & 0x1FFFF) * NC + j];
            __half_raw h1; h1.x = hw2s[(p.y & 0x1FFFF) * NC + j];
            __half_raw h2; h2.x = hw2s[(p.z & 0x1FFFF) * NC + j];
            __half_raw h3; h3.x = hw2s[(p.w & 0x1FFFF) * NC + j];
            acc = fmaf(h2f_lo(((unsigned)p.x) >> 17), __half2float(*(__half*)&h0), acc);
            acc = fmaf(h2f_lo(((unsigned)p.y) >> 17), __half2float(*(__half*)&h1), acc);
            acc = fmaf(h2f_lo(((unsigned)p.z) >> 17), __half2float(*(__half*)&h2), acc);
            acc = fmaf(h2f_lo(((unsigned)p.w) >> 17), __half2float(*(__half*)&h3), acc);
        }
        for (; k < e; ++k) {
            int p0 = pbkt[k];
            __half_raw h0; h0.x = hw2s[(p0 & 0x1FFFF) * NC + j];
            acc = fmaf(h2f_lo(((unsigned)p0) >> 17), __half2float(*(__half*)&h0), acc);
        }
        { __half_raw hs; hs.x = hw2s[i * NC + j]; acc += __half2float(*(__half*)&hs); }
        v = fmaf(dinv[i], acc, b2[j]);
    } else {
        v = -1e30f;
    }
    float m = v;
    #pragma unroll
    for (int mask = 8; mask > 0; mask >>= 1) m = fmaxf(m, __shfl_xor(m, mask, HID));
    float ev = (j < NC) ? __expf(v - m) : 0.f;
    float ssum = ev;
    #pragma unroll
    for (int mask = 8; mask > 0; mask >>= 1) ssum += __shfl_xor(ssum, mask, HID);
    if (j < NC) out[(long)i * NC + j] = v - m - __logf(ssum);
}

// ---- launch -----------------------------------------------------------------

extern "C" void kernel_launch(void* const* d_in, const int* in_sizes, int n_in,
                              void* d_out, int out_size, void* d_ws, size_t ws_size,
                              hipStream_t stream) {
    const float* x  = (const float*)d_in[0];
    const int*   ei = (const int*)d_in[1];
    const float* ew = (const float*)d_in[2];
    const float* W1 = (const float*)d_in[3];
    const float* b1 = (const float*)d_in[4];
    const float* W2 = (const float*)d_in[5];
    const float* b2 = (const float*)d_in[6];
    float* out = (float*)d_out;

    const int* row = ei;
    const int* col = ei + NE;

    // workspace (words); xws overlays hist (dead after k_scatter)
    int*   hist   = (int*)d_ws;                    // NSEG*NB = 800,256
    int*   psum   = hist + NSEG * NB;              // NCH*NB  = 12,504
    int*   bstart = psum + NCH * NB;               // NB+1    = 1,564
    float* dinv   = (float*)(bstart + NB + 1);     // 100,000
    int*   ns     = (int*)(dinv + NN);             // 100,001
    size_t o = (size_t)(NSEG * NB) + NCH * NB + (NB + 1) + NN + (NN + 1);
    o = (o + 3) & ~(size_t)3;                      // 16B align (int2 bkt, int4 pbkt)
    int2*  bkt    = (int2*)((int*)d_ws + o);       // NE int2 = 6,400,000 w
    unsigned short* hw2s = (unsigned short*)(bkt + NE);   // NN*NC halves = 500,000 w
    int*   pbkt   = (int*)(hw2s + (size_t)NN * NC);       // NE words, 16B-aligned
    int2*  xws    = (int2*)hist;                   // NN*4 int2 = 800,000 w overlay
    // total ~= 11.1 M words = 44.5 MB (ws is 480 MB)

    k_hist<<<NSEG, 512, 0, stream>>>(col, hist);
    k_psumA<<<dim3((NB + 255) / 256, NCH), 256, 0, stream>>>(hist, psum);
    k_scanAll<<<1, 256, 0, stream>>>(psum, bstart);
    k_applyC<<<dim3((NB + 255) / 256, NCH), 256, 0, stream>>>(hist, psum, bstart);
    k_scatter<<<NSEG, 512, 0, stream>>>(row, col, ew, hist, bkt);

    // 1563 blocks: block = bucket; 4 waves = 4 MFMA tiles = 64 nodes
    k_xw<<<NB, 256, 0, stream>>>(x, W1, bstart, bkt, dinv, xws);
    k_rg1<<<NB, 256, 0, stream>>>(bstart, bkt, dinv, ns, (const unsigned short*)xws,
                                  b1, W2, hw2s, pbkt);
    k_gather2<<<(NN * 16) / 256, 256, 0, stream>>>(ns, pbkt, hw2s, dinv, b2, out);
}

// Round 9
// 351.707 us; speedup vs baseline: 1.4555x; 1.0280x over previous
//
#include <hip/hip_runtime.h>
#include <hip/hip_fp16.h>

#define NN 100000
#define NE 3200000
#define FIN 300
#define HID 16
#define NC 10

#define NPB 64                  // nodes per bucket
#define NB 1563                 // ceil(NN / NPB)
#define NSEG 512                // edge segments
#define EPS (NE / NSEG)         // 6250 edges per segment
#define NCH 8                   // chunks for the seg-scan
#define SEGPC (NSEG / NCH)      // 64 segs per chunk
#define CAP 4096                // max bucket size (mean 2048, sd ~45)

#define NTILE 6250              // NN / 16 node-tiles for MFMA k_xw

typedef __fp16 h2 __attribute__((ext_vector_type(2)));
typedef __fp16 h8 __attribute__((ext_vector_type(8)));
typedef float f32x4 __attribute__((ext_vector_type(4)));

__device__ __forceinline__ float h2f_lo(int y) {
    __half_raw hr; hr.x = (unsigned short)(y & 0xFFFF);
    __half h; *(__half_raw*)&h = hr;
    return __half2float(h);
}
__device__ __forceinline__ int f2h_us(float f) {
    __half h = __float2half(f);
    return (int)(*(__half_raw*)&h).x;
}

// pack 8 f32 (two f32x4) -> h8 via cvt_pkrtz, no elementwise movs
__device__ __forceinline__ h8 pack8(f32x4 u0, f32x4 u1) {
    union { h2 p; unsigned u; } c0, c1, c2, c3;
    c0.p = __builtin_amdgcn_cvt_pkrtz(u0[0], u0[1]);
    c1.p = __builtin_amdgcn_cvt_pkrtz(u0[2], u0[3]);
    c2.p = __builtin_amdgcn_cvt_pkrtz(u1[0], u1[1]);
    c3.p = __builtin_amdgcn_cvt_pkrtz(u1[2], u1[3]);
    union { uint4 u; h8 h; } r;
    r.u = make_uint4(c0.u, c1.u, c2.u, c3.u);
    return r.h;
}

// block exclusive scan via wave shuffle + cross-wave LDS (2 barriers)
__device__ __forceinline__ int blockScanExcl(int v, int tid, int* wsum) {
    int incl = v;
    #pragma unroll
    for (int off = 1; off < 64; off <<= 1) {
        int t2 = __shfl_up(incl, off, 64);
        if ((tid & 63) >= off) incl += t2;
    }
    int wid = tid >> 6;
    if ((tid & 63) == 63) wsum[wid] = incl;
    __syncthreads();
    int wof = 0;
    for (int w2 = 0; w2 < wid; ++w2) wof += wsum[w2];
    __syncthreads();
    return wof + incl - v;
}

// ---- phase 1: per-segment histogram over buckets ---------------------------

__launch_bounds__(512)
__global__ void k_hist(const int* __restrict__ col, int* __restrict__ hist) {
    __shared__ int bins[NB];
    int seg = blockIdx.x, tid = threadIdx.x;
    for (int i = tid; i < NB; i += 512) bins[i] = 0;
    __syncthreads();
    int base = seg * EPS;
    for (int k = tid; k < EPS; k += 512) atomicAdd(&bins[col[base + k] >> 6], 1);
    __syncthreads();
    for (int i = tid; i < NB; i += 512) hist[seg * NB + i] = bins[i];
}

// ---- phase 2: parallel scan of hist over segs ------------------------------

__global__ void k_psumA(const int* __restrict__ hist, int* __restrict__ psum) {
    int bin = blockIdx.x * 256 + threadIdx.x;
    int ch = blockIdx.y;
    if (bin >= NB) return;
    int s = 0;
    for (int seg = ch * SEGPC; seg < (ch + 1) * SEGPC; ++seg) s += hist[seg * NB + bin];
    psum[ch * NB + bin] = s;
}

// fused psumB + scanBkt: single block; per-bin chunk-scan then block scan
__global__ void k_scanAll(int* __restrict__ psum, int* __restrict__ bstart) {
    __shared__ int wsum[4];
    int t = threadIdx.x;
    const int M = (NB + 255) / 256;   // 7
    int base = t * M;
    int tot[M];
    int s = 0;
    #pragma unroll
    for (int q = 0; q < M; ++q) {
        int bin = base + q;
        int bt = 0;
        if (bin < NB) {
            int run = 0;
            #pragma unroll
            for (int ch = 0; ch < NCH; ++ch) {
                int v = psum[ch * NB + bin];
                psum[ch * NB + bin] = run;
                run += v;
            }
            bt = run;
        }
        tot[q] = bt;
        s += bt;
    }
    int run = blockScanExcl(s, t, wsum);
    #pragma unroll
    for (int q = 0; q < M; ++q) {
        int bin = base + q;
        if (bin < NB) { bstart[bin] = run; run += tot[q]; }
    }
    if (t == 255) bstart[NB] = run;   // = NE
}

__global__ void k_applyC(int* __restrict__ hist, const int* __restrict__ psum,
                         const int* __restrict__ bstart) {
    int bin = blockIdx.x * 256 + threadIdx.x;
    int ch = blockIdx.y;
    if (bin >= NB) return;
    int run = bstart[bin] + psum[ch * NB + bin];
    for (int seg = ch * SEGPC; seg < (ch + 1) * SEGPC; ++seg) {
        int idx = seg * NB + bin;
        int v = hist[idx];
        hist[idx] = run;
        run += v;
    }
}

// ---- phase 3: LDS-sorted scatter, coalesced int2 writes --------------------
// record: .x = row | (col&63)<<17 ; .y = w_half | bin<<16 (bin bits scrubbed later)
// NO global atomics (round-5 lesson: memory-side on MI355X, +120us).

__launch_bounds__(512)
__global__ void k_scatter(const int* __restrict__ row, const int* __restrict__ col,
                          const float* __restrict__ w, const int* __restrict__ hist,
                          int2* __restrict__ bkt) {
    __shared__ int bins[NB];
    __shared__ int cur[NB];
    __shared__ int wsum[8];
    __shared__ int2 sdata[EPS];
    int seg = blockIdx.x, tid = threadIdx.x;
    for (int i = tid; i < NB; i += 512) bins[i] = 0;
    __syncthreads();
    int base = seg * EPS;
    for (int k = tid; k < EPS; k += 512) atomicAdd(&bins[col[base + k] >> 6], 1);
    __syncthreads();
    // block exclusive scan of bins (shuffle-based, 2 barriers)
    const int M = (NB + 511) / 512;   // 4
    int lbase = tid * M;
    int s = 0;
    #pragma unroll
    for (int q = 0; q < M; ++q) { int i = lbase + q; if (i < NB) s += bins[i]; }
    int run = blockScanExcl(s, tid, wsum);
    #pragma unroll
    for (int q = 0; q < M; ++q) {
        int i = lbase + q;
        if (i < NB) { int v = bins[i]; bins[i] = run; cur[i] = run; run += v; }
    }
    __syncthreads();
    // place into LDS sorted by bin
    for (int k = tid; k < EPS; k += 512) {
        int e = base + k;
        int r = row[e], c = col[e];
        int bin = c >> 6;
        int pos = atomicAdd(&cur[bin], 1);
        sdata[pos] = make_int2(r | ((c & 63) << 17), f2h_us(w[e]) | (bin << 16));
    }
    __syncthreads();
    // bins[bin] := global_start(seg,bin) - lds_start(bin)
    for (int i = tid; i < NB; i += 512) bins[i] = hist[seg * NB + i] - bins[i];
    __syncthreads();
    for (int j = tid; j < EPS; j += 512) {
        int2 d = sdata[j];
        int bin = ((unsigned)d.y) >> 16;
        bkt[bins[bin] + j] = d;
    }
}

// ---- x @ W1 via MFMA + fused per-bucket wdeg/dinv --------------------------
// Block = 1 bucket = 64 nodes = 4 MFMA tiles (1 per wave). Phase A: stream the
// bucket's edges, LDS-atomicAdd wdeg[64], write dinv[]. Phase B: 16x16x32 f16
// MFMA over K=320 (zero-padded), C-write scaled by dinv.

__launch_bounds__(256)
__global__ void k_xw(const float* __restrict__ x, const float* __restrict__ W1,
                     const int* __restrict__ bstart, const int2* __restrict__ bkt,
                     float* __restrict__ dinv, int2* __restrict__ xws) {
    __shared__ h8 bfrag[10][64];        // 10 KB, frag-ordered W1 in f16
    __shared__ float wd[NPB];
    int tid = threadIdx.x;
    int b = blockIdx.x;                 // bucket
    if (tid < NPB) wd[tid] = 1.0f;      // self-loop weight
    // stage + convert W1: entry (s,l): col=l&15, k = 32s + 8*(l>>4) + j
    for (int e2 = tid; e2 < 640; e2 += 256) {
        int s = e2 >> 6, l = e2 & 63;
        int g = l >> 4, c = l & 15;
        int kb = 32 * s + 8 * g;
        f32x4 u0, u1;
        #pragma unroll
        for (int j = 0; j < 4; ++j) {
            int k = kb + j;
            u0[j] = (k < FIN) ? W1[k * HID + c] : 0.f;
        }
        #pragma unroll
        for (int j = 0; j < 4; ++j) {
            int k = kb + 4 + j;
            u1[j] = (k < FIN) ? W1[k * HID + c] : 0.f;
        }
        bfrag[s][l] = pack8(u0, u1);
    }
    __syncthreads();
    // phase A: wdeg for bucket b (all records here have bin == b)
    int es = bstart[b], ee = bstart[b + 1];
    for (int k = es + tid; k < ee; k += 256) {
        int2 d = bkt[k];
        atomicAdd(&wd[(d.x >> 17) & 63], h2f_lo(d.y));
    }
    __syncthreads();
    if (tid < NPB) {
        int node = b * NPB + tid;
        float di = rsqrtf(wd[tid]);
        wd[tid] = di;
        if (node < NN) dinv[node] = di;
    }
    __syncthreads();
    // phase B: MFMA, 1 tile per wave
    int widx = tid >> 6, lane = tid & 63;
    int g = lane >> 4, rr = lane & 15;
    int tile = b * 4 + widx;
    unsigned short* op = (unsigned short*)xws;
    if (tile < NTILE) {
        int n0 = tile * 16;
        const float* xrow = x + (long)(n0 + rr) * FIN;
        f32x4 acc = {0.f, 0.f, 0.f, 0.f};
        #pragma unroll
        for (int s = 0; s < 9; ++s) {
            int k0 = 32 * s + 8 * g;
            f32x4 u0 = *(const f32x4*)(xrow + k0);
            f32x4 u1 = *(const f32x4*)(xrow + k0 + 4);
            acc = __builtin_amdgcn_mfma_f32_16x16x32_f16(pack8(u0, u1), bfrag[s][lane], acc, 0, 0, 0);
        }
        {   // K tail: k 288..299 valid, 300..319 zero
            int k0 = 288 + 8 * g;
            f32x4 z = {0.f, 0.f, 0.f, 0.f};
            f32x4 u0 = (g < 2) ? *(const f32x4*)(xrow + k0) : z;
            f32x4 u1 = (g == 0) ? *(const f32x4*)(xrow + k0 + 4) : z;
            acc = __builtin_amdgcn_mfma_f32_16x16x32_f16(pack8(u0, u1), bfrag[9][lane], acc, 0, 0, 0);
        }
        // C/D: col = lane&15 (=rr), row-in-tile = g*4 + r2
        #pragma unroll
        for (int r2 = 0; r2 < 4; ++r2) {
            int node = n0 + g * 4 + r2;
            float di = wd[widx * 16 + g * 4 + r2];
            op[(long)node * HID + rr] = (unsigned short)f2h_us(di * acc[r2]);
        }
    }
}

// ---- fused refine + layer-1 gather (512 threads) ---------------------------
// Per bucket: count/scan/sort edges into LDS (node order), emit PACKED 4-byte
// records (src:17 | w_fp16:15) for k_gather2, then gather layer 1 straight
// from LDS, fused b1/relu/@W2, fp16 store. 512 threads: 2x lanes for
// count/sort/write phases, gather q-loop 4 -> 2 nodes/thread, 32 waves/CU.

__launch_bounds__(512)
__global__ void k_rg1(const int* __restrict__ bstart, const int2* __restrict__ bkt,
                      const float* __restrict__ dinv, int* __restrict__ ns,
                      const unsigned short* __restrict__ xwsh,
                      const float* __restrict__ b1, const float* __restrict__ W2,
                      unsigned short* __restrict__ hw2s, int* __restrict__ pbkt) {
    __shared__ int cnt[NPB];
    __shared__ int cur[NPB];
    __shared__ int off[NPB + 1];
    __shared__ int2 sorted[CAP];
    __shared__ float w2s[HID * NC];
    __shared__ float b1s[HID];
    int b = blockIdx.x, tid = threadIdx.x;
    if (tid < HID * NC) w2s[tid] = W2[tid];
    if (tid < HID) b1s[tid] = b1[tid];
    int s = bstart[b], e = bstart[b + 1];
    int size = e - s; if (size > CAP) size = CAP;   // 45-sigma guard, never hit
    if (tid < NPB) cnt[tid] = 0;
    __syncthreads();
    for (int k = tid; k < size; k += 512) {
        int2 d = bkt[s + k];
        atomicAdd(&cnt[(d.x >> 17) & 63], 1);
    }
    __syncthreads();
    // 64-class exclusive scan: single wave (threads 0..63), shuffle-based
    if (tid < NPB) {
        int vcl = cnt[tid];
        int incl = vcl;
        #pragma unroll
        for (int o = 1; o < 64; o <<= 1) {
            int t2 = __shfl_up(incl, o, 64);
            if (tid >= o) incl += t2;
        }
        int excl = incl - vcl;
        cur[tid] = excl;
        off[tid] = excl;
        int node = b * NPB + tid;
        if (node < NN) ns[node] = s + excl;
        if (tid == 0) off[NPB] = size;
    }
    if (b == NB - 1 && tid == 0) ns[NN] = e;
    __syncthreads();
    for (int k = tid; k < size; k += 512) {
        int2 d = bkt[s + k];
        int cl = (d.x >> 17) & 63;
        int pos = atomicAdd(&cur[cl], 1);
        sorted[pos] = make_int2(d.x & 0x1FFFF, d.y & 0xFFFF);
    }
    __syncthreads();
    // packed node-sorted edges for k_gather2: src | whalf<<17 (w >= 0)
    for (int k = tid; k < size; k += 512) {
        int2 d = sorted[k];
        pbkt[s + k] = d.x | (d.y << 17);
    }
    // layer-1 gather from LDS: 32 node-groups x 16 cols, 2 nodes/thread
    int c = tid & 15, g2 = tid >> 4;   // g2 in 0..31
    #pragma unroll 1
    for (int q = 0; q < 2; ++q) {
        int nl = g2 + 32 * q;
        int node = b * NPB + nl;
        int o0 = off[nl], o1 = off[nl + 1];
        float acc = 0.f;
        int k = o0;
        for (; k + 4 <= o1; k += 4) {
            int2 e0 = sorted[k], e1 = sorted[k + 1], e2 = sorted[k + 2], e3 = sorted[k + 3];
            __half_raw h0; h0.x = xwsh[e0.x * HID + c];
            __half_raw h1; h1.x = xwsh[e1.x * HID + c];
            __half_raw h2; h2.x = xwsh[e2.x * HID + c];
            __half_raw h3; h3.x = xwsh[e3.x * HID + c];
            acc = fmaf(h2f_lo(e0.y), __half2float(*(__half*)&h0), acc);
            acc = fmaf(h2f_lo(e1.y), __half2float(*(__half*)&h1), acc);
            acc = fmaf(h2f_lo(e2.y), __half2float(*(__half*)&h2), acc);
            acc = fmaf(h2f_lo(e3.y), __half2float(*(__half*)&h3), acc);
        }
        for (; k < o1; ++k) {
            int2 e0 = sorted[k];
            __half_raw h0; h0.x = xwsh[e0.x * HID + c];
            acc = fmaf(h2f_lo(e0.y), __half2float(*(__half*)&h0), acc);
        }
        if (node < NN) {
            { __half_raw hs; hs.x = xwsh[node * HID + c]; acc += __half2float(*(__half*)&hs); }
            float dc = dinv[node];
            float h = fmaxf(fmaf(dc, acc, b1s[c]), 0.f);
            float acc2 = 0.f;
            int jj = (c < NC) ? c : 0;
            #pragma unroll
            for (int k2 = 0; k2 < HID; ++k2) {
                float hk = __shfl(h, k2, HID);
                acc2 = fmaf(hk, w2s[k2 * NC + jj], acc2);
            }
            if (c < NC) hw2s[node * NC + c] = (unsigned short)f2h_us(dc * acc2);
        }
    }
}

// ---- layer 2 pull-gather: 32 lanes/node (col x edge-half), b2/log_softmax --
// Halves the serial dependent-load chain per thread vs 16 lanes/node; one
// shfl_xor(16) combines the two halves.

__global__ void k_gather2(const int* __restrict__ ns, const int* __restrict__ pbkt,
                          const unsigned short* __restrict__ hw2s,
                          const float* __restrict__ dinv, const float* __restrict__ b2,
                          float* __restrict__ out) {
    int t = blockIdx.x * 256 + threadIdx.x;
    int i = t >> 5;                    // node
    int lane5 = t & 31;
    int j = lane5 & 15;                // col
    int h = lane5 >> 4;                // edge-half
    int s = ns[i], e = ns[i + 1];
    float acc = 0.f;
    if (j < NC) {
        int k = s + h;
        for (; k + 6 < e; k += 8) {
            int p0 = pbkt[k], p1 = pbkt[k + 2], p2 = pbkt[k + 4], p3 = pbkt[k + 6];
            __half_raw h0; h0.x = hw2s[(p0 & 0x1FFFF) * NC + j];
            __half_raw h1; h1.x = hw2s[(p1 & 0x1FFFF) * NC + j];
            __half_raw h2; h2.x = hw2s[(p2 & 0x1FFFF) * NC + j];
            __half_raw h3; h3.x = hw2s[(p3 & 0x1FFFF) * NC + j];
            acc = fmaf(h2f_lo(((unsigned)p0) >> 17), __half2float(*(__half*)&h0), acc);
            acc = fmaf(h2f_lo(((unsigned)p1) >> 17), __half2float(*(__half*)&h1), acc);
            acc = fmaf(h2f_lo(((unsigned)p2) >> 17), __half2float(*(__half*)&h2), acc);
            acc = fmaf(h2f_lo(((unsigned)p3) >> 17), __half2float(*(__half*)&h3), acc);
        }
        for (; k < e; k += 2) {
            int p0 = pbkt[k];
            __half_raw h0; h0.x = hw2s[(p0 & 0x1FFFF) * NC + j];
            acc = fmaf(h2f_lo(((unsigned)p0) >> 17), __half2float(*(__half*)&h0), acc);
        }
    }
    // combine the two edge-halves within the 32-lane node group
    acc += __shfl_xor(acc, 16, 32);
    float v;
    if (j < NC && h == 0) {
        __half_raw hs; hs.x = hw2s[i * NC + j];
        acc += __half2float(*(__half*)&hs);
        v = fmaf(dinv[i], acc, b2[j]);
    } else {
        v = -1e30f;
    }
    float m = v;
    #pragma unroll
    for (int mask = 8; mask > 0; mask >>= 1) m = fmaxf(m, __shfl_xor(m, mask, HID));
    float ev = (j < NC && h == 0) ? __expf(v - m) : 0.f;
    float ssum = ev;
    #pragma unroll
    for (int mask = 8; mask > 0; mask >>= 1) ssum += __shfl_xor(ssum, mask, HID);
    if (j < NC && h == 0) out[(long)i * NC + j] = v - m - __logf(ssum);
}

// ---- launch -----------------------------------------------------------------

extern "C" void kernel_launch(void* const* d_in, const int* in_sizes, int n_in,
                              void* d_out, int out_size, void* d_ws, size_t ws_size,
                              hipStream_t stream) {
    const float* x  = (const float*)d_in[0];
    const int*   ei = (const int*)d_in[1];
    const float* ew = (const float*)d_in[2];
    const float* W1 = (const float*)d_in[3];
    const float* b1 = (const float*)d_in[4];
    const float* W2 = (const float*)d_in[5];
    const float* b2 = (const float*)d_in[6];
    float* out = (float*)d_out;

    const int* row = ei;
    const int* col = ei + NE;

    // workspace (words); xws overlays hist (dead after k_scatter)
    int*   hist   = (int*)d_ws;                    // NSEG*NB = 800,256
    int*   psum   = hist + NSEG * NB;              // NCH*NB  = 12,504
    int*   bstart = psum + NCH * NB;               // NB+1    = 1,564
    float* dinv   = (float*)(bstart + NB + 1);     // 100,000
    int*   ns     = (int*)(dinv + NN);             // 100,001
    size_t o = (size_t)(NSEG * NB) + NCH * NB + (NB + 1) + NN + (NN + 1);
    o = (o + 3) & ~(size_t)3;                      // 16B align (int2 bkt, int4 pbkt)
    int2*  bkt    = (int2*)((int*)d_ws + o);       // NE int2 = 6,400,000 w
    unsigned short* hw2s = (unsigned short*)(bkt + NE);   // NN*NC halves = 500,000 w
    int*   pbkt   = (int*)(hw2s + (size_t)NN * NC);       // NE words, 16B-aligned
    int2*  xws    = (int2*)hist;                   // NN*4 int2 = 800,000 w overlay
    // total ~= 11.1 M words = 44.5 MB (ws is 480 MB)

    k_hist<<<NSEG, 512, 0, stream>>>(col, hist);
    k_psumA<<<dim3((NB + 255) / 256, NCH), 256, 0, stream>>>(hist, psum);
    k_scanAll<<<1, 256, 0, stream>>>(psum, bstart);
    k_applyC<<<dim3((NB + 255) / 256, NCH), 256, 0, stream>>>(hist, psum, bstart);
    k_scatter<<<NSEG, 512, 0, stream>>>(row, col, ew, hist, bkt);

    // 1563 blocks: block = bucket; 4 waves = 4 MFMA tiles = 64 nodes
    k_xw<<<NB, 256, 0, stream>>>(x, W1, bstart, bkt, dinv, xws);
    k_rg1<<<NB, 512, 0, stream>>>(bstart, bkt, dinv, ns, (const unsigned short*)xws,
                                  b1, W2, hw2s, pbkt);
    k_gather2<<<(NN * 32) / 256, 256, 0, stream>>>(ns, pbkt, hw2s, dinv, b2, out);
}